// Round 1
// baseline (1784.032 us; speedup 1.0000x reference)
//
#include <hip/hip_runtime.h>
#include <hip/hip_bf16.h>

#define N_NODES 100000
#define N_EDGES 1600000
#define ETOT (N_EDGES + N_NODES)
#define NFEAT 165
#define HID 128
#define NCLS 2
#define NEG 0.2f

// ---- workspace layout (units of 4 bytes) ----
#define OFF_FLAG 0
#define OFF_W 16
// weight sub-offsets (within wb = ws + OFF_W)
#define WO_W1L 0
#define WO_B1L 21120
#define WO_W1R 21248
#define WO_B1R 42368
#define WO_ATT1 42496
#define WO_BIAS1 42624
#define WO_W2L 42752
#define WO_B2L 43008
#define WO_W2R 43010
#define WO_B2R 43266
#define WO_ATT2 43268
#define WO_BIAS2 43270
#define W_TOTAL 43272

#define OFF_XL1 43392
#define OFF_XR1 (OFF_XL1 + N_NODES * HID)        // also reused as out1 / h
#define OFF_SCORE (OFF_XR1 + N_NODES * HID)
#define OFF_ZERO (OFF_SCORE + ETOT)              // contiguous zero-init block
#define OFF_MKEY  (OFF_ZERO)
#define OFF_DEN   (OFF_ZERO + N_NODES)
#define OFF_MKEY2 (OFF_ZERO + 2 * N_NODES)
#define OFF_DEN2  (OFF_ZERO + 3 * N_NODES)
#define OFF_OUT2  (OFF_ZERO + 4 * N_NODES)
#define ZERO_CNT  (6 * N_NODES)
#define OFF_XL2 (OFF_ZERO + ZERO_CNT)
#define OFF_XR2 (OFF_XL2 + N_NODES * NCLS)
#define OFF_SCORE2 (OFF_XR2 + N_NODES * NCLS)

__device__ __forceinline__ float bload(const void* p, size_t i) {
    unsigned u = ((const unsigned short*)p)[i];
    return __uint_as_float(u << 16);
}

// order-preserving float->uint key for atomicMax
__device__ __forceinline__ unsigned fkey(float f) {
    unsigned b = __float_as_uint(f);
    return (b & 0x80000000u) ? ~b : (b | 0x80000000u);
}
__device__ __forceinline__ float funkey(unsigned k) {
    unsigned b = (k & 0x80000000u) ? (k & 0x7FFFFFFFu) : ~k;
    return __uint_as_float(b);
}

__device__ __forceinline__ float lrelu(float v) { return v > 0.f ? v : NEG * v; }

// ---- dtype detection: are the float tensors bf16-packed or fp32? ----
// If bf16: every uint16 half is a plausible bf16 sample of N(0,1).
// If fp32: only the high halves are plausible; low halves are mantissa noise.
__global__ void k_detect(const unsigned short* __restrict__ x16, unsigned* flag) {
    __shared__ int cnt;
    if (threadIdx.x == 0) cnt = 0;
    __syncthreads();
    int c = 0;
    for (int t = 0; t < 2; t++) {
        unsigned short h = x16[threadIdx.x * 2 + t];
        unsigned e = (h >> 7) & 0xFF;
        if ((h & 0x7FFF) == 0 || (e >= 100 && e <= 140)) c++;
    }
    atomicAdd(&cnt, c);
    __syncthreads();
    if (threadIdx.x == 0) *flag = (cnt >= 384) ? 1u : 0u;  // 75% of 512
}

// ---- convert all weight tensors to fp32 in workspace ----
__global__ void k_cvt_w(const unsigned* __restrict__ flag,
                        const void* s0, const void* s1, const void* s2, const void* s3,
                        const void* s4, const void* s5, const void* s6, const void* s7,
                        const void* s8, const void* s9, const void* s10, const void* s11,
                        float* __restrict__ dst) {
    int i = blockIdx.x * blockDim.x + threadIdx.x;
    if (i >= W_TOTAL) return;
    const void* src; int off;
    if      (i < WO_B1L)   { src = s0;  off = i; }
    else if (i < WO_W1R)   { src = s1;  off = i - WO_B1L; }
    else if (i < WO_B1R)   { src = s2;  off = i - WO_W1R; }
    else if (i < WO_ATT1)  { src = s3;  off = i - WO_B1R; }
    else if (i < WO_BIAS1) { src = s4;  off = i - WO_ATT1; }
    else if (i < WO_W2L)   { src = s5;  off = i - WO_BIAS1; }
    else if (i < WO_B2L)   { src = s6;  off = i - WO_W2L; }
    else if (i < WO_W2R)   { src = s7;  off = i - WO_B2L; }
    else if (i < WO_B2R)   { src = s8;  off = i - WO_W2R; }
    else if (i < WO_ATT2)  { src = s9;  off = i - WO_B2R; }
    else if (i < WO_BIAS2) { src = s10; off = i - WO_ATT2; }
    else                   { src = s11; off = i - WO_BIAS2; }
    dst[i] = (*flag) ? bload(src, off) : ((const float*)src)[off];
}

// ---- layer-1 GEMMs (fused l/r): xl = x@W1l+b1l, xr = x@W1r+b1r ----
// 8 nodes per 128-thread block; x rows staged in LDS; W streamed (L2-resident).
__global__ void __launch_bounds__(128) k_gemm1(const void* __restrict__ x,
                                               const unsigned* __restrict__ flag,
                                               const float* __restrict__ wb,
                                               float* __restrict__ xl, float* __restrict__ xr) {
    __shared__ float xs[8 * NFEAT];
    const float* W1l = wb + WO_W1L;
    const float* b1l = wb + WO_B1L;
    const float* W1r = wb + WO_W1R;
    const float* b1r = wb + WO_B1R;
    int node0 = blockIdx.x * 8;
    unsigned isbf = *flag;
    for (int idx = threadIdx.x; idx < 8 * NFEAT; idx += 128) {
        int n = idx / NFEAT, k = idx - n * NFEAT;
        size_t g = (size_t)(node0 + n) * NFEAT + k;
        xs[idx] = isbf ? bload(x, g) : ((const float*)x)[g];
    }
    __syncthreads();
    int j = threadIdx.x;
    float accl[8], accr[8];
#pragma unroll
    for (int n = 0; n < 8; n++) { accl[n] = b1l[j]; accr[n] = b1r[j]; }
    for (int k = 0; k < NFEAT; k++) {
        float wl = W1l[k * HID + j];
        float wr = W1r[k * HID + j];
#pragma unroll
        for (int n = 0; n < 8; n++) {
            float xv = xs[n * NFEAT + k];
            accl[n] = fmaf(xv, wl, accl[n]);
            accr[n] = fmaf(xv, wr, accr[n]);
        }
    }
#pragma unroll
    for (int n = 0; n < 8; n++) {
        size_t o = (size_t)(node0 + n) * HID + j;
        xl[o] = accl[n];
        xr[o] = accr[n];
    }
}

// ---- layer-1 edge score + segment max (wave per edge) ----
__global__ void __launch_bounds__(256) k_edge_score1(const int* __restrict__ esrc,
                                                     const int* __restrict__ edst,
                                                     const float* __restrict__ xl,
                                                     const float* __restrict__ xr,
                                                     const float* __restrict__ att,
                                                     float* __restrict__ score,
                                                     unsigned* __restrict__ mkey) {
    int wave = threadIdx.x >> 6, lane = threadIdx.x & 63;
    int e = blockIdx.x * 4 + wave;
    if (e >= ETOT) return;
    int s = (e < N_EDGES) ? esrc[e] : (e - N_EDGES);
    int d = (e < N_EDGES) ? edst[e] : (e - N_EDGES);
    const float* a0 = xl + (size_t)s * HID;
    const float* b0 = xr + (size_t)d * HID;
    float v0 = lrelu(a0[lane] + b0[lane]);
    float p = att[lane] * v0;
    float v1 = lrelu(a0[lane + 64] + b0[lane + 64]);
    p = fmaf(att[lane + 64], v1, p);
#pragma unroll
    for (int off = 32; off > 0; off >>= 1) p += __shfl_down(p, off);
    if (lane == 0) {
        score[e] = p;
        atomicMax(&mkey[d], fkey(p));
    }
}

// ---- exp(score - m[dst]) and denom accumulation (generic, both layers) ----
__global__ void k_edge_exp(const int* __restrict__ edst, float* __restrict__ score,
                           const unsigned* __restrict__ mkey, float* __restrict__ den) {
    int e = blockIdx.x * blockDim.x + threadIdx.x;
    if (e >= ETOT) return;
    int d = (e < N_EDGES) ? edst[e] : (e - N_EDGES);
    float a = expf(score[e] - funkey(mkey[d]));
    score[e] = a;
    atomicAdd(&den[d], a);
}

// ---- layer-1 weighted scatter: out[dst] += alpha * xl[src] (wave per edge) ----
__global__ void __launch_bounds__(256) k_edge_agg1(const int* __restrict__ esrc,
                                                   const int* __restrict__ edst,
                                                   const float* __restrict__ xl,
                                                   const float* __restrict__ score,
                                                   const float* __restrict__ den,
                                                   float* __restrict__ out) {
    int wave = threadIdx.x >> 6, lane = threadIdx.x & 63;
    int e = blockIdx.x * 4 + wave;
    if (e >= ETOT) return;
    int s = (e < N_EDGES) ? esrc[e] : (e - N_EDGES);
    int d = (e < N_EDGES) ? edst[e] : (e - N_EDGES);
    float w = score[e] / den[d];
    const float* a0 = xl + (size_t)s * HID;
    float* o = out + (size_t)d * HID;
    atomicAdd(&o[lane], w * a0[lane]);
    atomicAdd(&o[lane + 64], w * a0[lane + 64]);
}

// ---- h = relu(out1 + bias1), in place ----
__global__ void k_relu_bias(float* __restrict__ h, const float* __restrict__ bias) {
    int i = blockIdx.x * blockDim.x + threadIdx.x;
    if (i >= N_NODES * HID) return;
    float v = h[i] + bias[i & (HID - 1)];
    h[i] = v > 0.f ? v : 0.f;
}

// ---- layer-2 GEMMs: wave per node, K=128 shuffle reduction, 4 outputs ----
__global__ void __launch_bounds__(256) k_gemm2(const float* __restrict__ h,
                                               const float* __restrict__ wb,
                                               float* __restrict__ xl2, float* __restrict__ xr2) {
    const float* W2l = wb + WO_W2L;
    const float* b2l = wb + WO_B2L;
    const float* W2r = wb + WO_W2R;
    const float* b2r = wb + WO_B2R;
    int wave = threadIdx.x >> 6, lane = threadIdx.x & 63;
    int node = blockIdx.x * 4 + wave;
    if (node >= N_NODES) return;
    const float* hr = h + (size_t)node * HID;
    float h0 = hr[lane], h1 = hr[lane + 64];
    float al0 = h0 * W2l[lane * 2 + 0] + h1 * W2l[(lane + 64) * 2 + 0];
    float al1 = h0 * W2l[lane * 2 + 1] + h1 * W2l[(lane + 64) * 2 + 1];
    float ar0 = h0 * W2r[lane * 2 + 0] + h1 * W2r[(lane + 64) * 2 + 0];
    float ar1 = h0 * W2r[lane * 2 + 1] + h1 * W2r[(lane + 64) * 2 + 1];
#pragma unroll
    for (int off = 32; off > 0; off >>= 1) {
        al0 += __shfl_down(al0, off);
        al1 += __shfl_down(al1, off);
        ar0 += __shfl_down(ar0, off);
        ar1 += __shfl_down(ar1, off);
    }
    if (lane == 0) {
        xl2[node * 2 + 0] = al0 + b2l[0];
        xl2[node * 2 + 1] = al1 + b2l[1];
        xr2[node * 2 + 0] = ar0 + b2r[0];
        xr2[node * 2 + 1] = ar1 + b2r[1];
    }
}

// ---- layer-2 edge score + segment max (thread per edge, D=2) ----
__global__ void k_edge_score2(const int* __restrict__ esrc, const int* __restrict__ edst,
                              const float* __restrict__ xl2, const float* __restrict__ xr2,
                              const float* __restrict__ wb,
                              float* __restrict__ score2, unsigned* __restrict__ mkey2) {
    int e = blockIdx.x * blockDim.x + threadIdx.x;
    if (e >= ETOT) return;
    int s = (e < N_EDGES) ? esrc[e] : (e - N_EDGES);
    int d = (e < N_EDGES) ? edst[e] : (e - N_EDGES);
    float a0 = lrelu(xl2[s * 2 + 0] + xr2[d * 2 + 0]);
    float a1 = lrelu(xl2[s * 2 + 1] + xr2[d * 2 + 1]);
    float p = wb[WO_ATT2] * a0 + wb[WO_ATT2 + 1] * a1;
    score2[e] = p;
    atomicMax(&mkey2[d], fkey(p));
}

// ---- layer-2 weighted scatter (thread per edge, D=2) ----
__global__ void k_edge_agg2(const int* __restrict__ esrc, const int* __restrict__ edst,
                            const float* __restrict__ xl2, const float* __restrict__ score2,
                            const float* __restrict__ den2, float* __restrict__ out2) {
    int e = blockIdx.x * blockDim.x + threadIdx.x;
    if (e >= ETOT) return;
    int s = (e < N_EDGES) ? esrc[e] : (e - N_EDGES);
    int d = (e < N_EDGES) ? edst[e] : (e - N_EDGES);
    float w = score2[e] / den2[d];
    atomicAdd(&out2[d * 2 + 0], w * xl2[s * 2 + 0]);
    atomicAdd(&out2[d * 2 + 1], w * xl2[s * 2 + 1]);
}

// ---- final: out = out2 + bias2, dtype-branched store ----
__global__ void k_final(const float* __restrict__ out2, const float* __restrict__ wb,
                        const unsigned* __restrict__ flag, void* __restrict__ dout) {
    int i = blockIdx.x * blockDim.x + threadIdx.x;
    if (i >= N_NODES * NCLS) return;
    float v = out2[i] + wb[WO_BIAS2 + (i & 1)];
    if (*flag)
        ((__hip_bfloat16*)dout)[i] = __float2bfloat16(v);
    else
        ((float*)dout)[i] = v;
}

extern "C" void kernel_launch(void* const* d_in, const int* in_sizes, int n_in,
                              void* d_out, int out_size, void* d_ws, size_t ws_size,
                              hipStream_t stream) {
    char* w = (char*)d_ws;
    unsigned* flag = (unsigned*)(w + (size_t)OFF_FLAG * 4);
    float* wb = (float*)(w + (size_t)OFF_W * 4);
    float* xl1 = (float*)(w + (size_t)OFF_XL1 * 4);
    float* xr1 = (float*)(w + (size_t)OFF_XR1 * 4);  // also out1 / h
    float* score = (float*)(w + (size_t)OFF_SCORE * 4);
    unsigned* mkey = (unsigned*)(w + (size_t)OFF_MKEY * 4);
    float* den = (float*)(w + (size_t)OFF_DEN * 4);
    unsigned* mkey2 = (unsigned*)(w + (size_t)OFF_MKEY2 * 4);
    float* den2 = (float*)(w + (size_t)OFF_DEN2 * 4);
    float* out2 = (float*)(w + (size_t)OFF_OUT2 * 4);
    float* xl2 = (float*)(w + (size_t)OFF_XL2 * 4);
    float* xr2 = (float*)(w + (size_t)OFF_XR2 * 4);
    float* score2 = (float*)(w + (size_t)OFF_SCORE2 * 4);
    const int* esrc = (const int*)d_in[1];
    const int* edst = (const int*)d_in[2];

    k_detect<<<1, 256, 0, stream>>>((const unsigned short*)d_in[0], flag);
    k_cvt_w<<<(W_TOTAL + 255) / 256, 256, 0, stream>>>(flag,
        d_in[3], d_in[4], d_in[5], d_in[6], d_in[7], d_in[8],
        d_in[9], d_in[10], d_in[11], d_in[12], d_in[13], d_in[14], wb);
    hipMemsetAsync(w + (size_t)OFF_ZERO * 4, 0, (size_t)ZERO_CNT * 4, stream);

    k_gemm1<<<N_NODES / 8, 128, 0, stream>>>(d_in[0], flag, wb, xl1, xr1);
    k_edge_score1<<<(ETOT + 3) / 4, 256, 0, stream>>>(esrc, edst, xl1, xr1,
                                                      wb + WO_ATT1, score, mkey);
    k_edge_exp<<<(ETOT + 255) / 256, 256, 0, stream>>>(edst, score, mkey, den);
    // xr1 is dead after score1 -> reuse as out1 accumulator
    hipMemsetAsync(xr1, 0, (size_t)N_NODES * HID * 4, stream);
    k_edge_agg1<<<(ETOT + 3) / 4, 256, 0, stream>>>(esrc, edst, xl1, score, den, xr1);
    k_relu_bias<<<(N_NODES * HID + 255) / 256, 256, 0, stream>>>(xr1, wb + WO_BIAS1);

    k_gemm2<<<(N_NODES + 3) / 4, 256, 0, stream>>>(xr1, wb, xl2, xr2);
    k_edge_score2<<<(ETOT + 255) / 256, 256, 0, stream>>>(esrc, edst, xl2, xr2, wb,
                                                          score2, mkey2);
    k_edge_exp<<<(ETOT + 255) / 256, 256, 0, stream>>>(edst, score2, mkey2, den2);
    k_edge_agg2<<<(ETOT + 255) / 256, 256, 0, stream>>>(esrc, edst, xl2, score2, den2, out2);
    k_final<<<(N_NODES * NCLS + 255) / 256, 256, 0, stream>>>(out2, wb, flag, d_out);
}

// Round 2
// 743.175 us; speedup vs baseline: 2.4006x; 2.4006x over previous
//
#include <hip/hip_runtime.h>
#include <hip/hip_bf16.h>

#define N_NODES 100000
#define N_EDGES 1600000
#define ETOT (N_EDGES + N_NODES)
#define NFEAT 165
#define HID 128
#define NCLS 2
#define NEG 0.2f
#define NBLK 391  // ceil(N_NODES/256)

// ---- workspace layout (units of 4 bytes) ----
#define OFF_FLAG 0
#define OFF_W 16
// weight sub-offsets (within wb = ws + OFF_W)
#define WO_W1L 0
#define WO_B1L 21120
#define WO_W1R 21248
#define WO_B1R 42368
#define WO_ATT1 42496
#define WO_BIAS1 42624
#define WO_W2L 42752
#define WO_B2L 43008
#define WO_W2R 43010
#define WO_B2R 43266
#define WO_ATT2 43268
#define WO_BIAS2 43270
#define W_TOTAL 43272

#define OFF_XL1 43392
#define OFF_XR1 (OFF_XL1 + N_NODES * HID)   // reused as h after k_gat1
#define OFF_CSR (OFF_XR1 + N_NODES * HID)   // csr_src[ETOT]
#define OFF_ROWPTR (OFF_CSR + ETOT)         // rowptr[N_NODES+1]
#define OFF_CURSOR (OFF_ROWPTR + N_NODES + 8)  // counts, then scatter cursor
#define OFF_BSUM (OFF_CURSOR + N_NODES)     // scan block sums [1024]
#define OFF_XL2 (OFF_BSUM + 1024)
#define OFF_XR2 (OFF_XL2 + N_NODES * NCLS)

__device__ __forceinline__ float bload(const void* p, size_t i) {
    unsigned u = ((const unsigned short*)p)[i];
    return __uint_as_float(u << 16);
}

__device__ __forceinline__ float lrelu(float v) { return v > 0.f ? v : NEG * v; }

// ---- dtype detection: are the float tensors bf16-packed or fp32? ----
__global__ void k_detect(const unsigned short* __restrict__ x16, unsigned* flag) {
    __shared__ int cnt;
    if (threadIdx.x == 0) cnt = 0;
    __syncthreads();
    int c = 0;
    for (int t = 0; t < 2; t++) {
        unsigned short h = x16[threadIdx.x * 2 + t];
        unsigned e = (h >> 7) & 0xFF;
        if ((h & 0x7FFF) == 0 || (e >= 100 && e <= 140)) c++;
    }
    atomicAdd(&cnt, c);
    __syncthreads();
    if (threadIdx.x == 0) *flag = (cnt >= 384) ? 1u : 0u;
}

// ---- convert all weight tensors to fp32 in workspace ----
__global__ void k_cvt_w(const unsigned* __restrict__ flag,
                        const void* s0, const void* s1, const void* s2, const void* s3,
                        const void* s4, const void* s5, const void* s6, const void* s7,
                        const void* s8, const void* s9, const void* s10, const void* s11,
                        float* __restrict__ dst) {
    int i = blockIdx.x * blockDim.x + threadIdx.x;
    if (i >= W_TOTAL) return;
    const void* src; int off;
    if      (i < WO_B1L)   { src = s0;  off = i; }
    else if (i < WO_W1R)   { src = s1;  off = i - WO_B1L; }
    else if (i < WO_B1R)   { src = s2;  off = i - WO_W1R; }
    else if (i < WO_ATT1)  { src = s3;  off = i - WO_B1R; }
    else if (i < WO_BIAS1) { src = s4;  off = i - WO_ATT1; }
    else if (i < WO_W2L)   { src = s5;  off = i - WO_BIAS1; }
    else if (i < WO_B2L)   { src = s6;  off = i - WO_W2L; }
    else if (i < WO_W2R)   { src = s7;  off = i - WO_B2L; }
    else if (i < WO_B2R)   { src = s8;  off = i - WO_W2R; }
    else if (i < WO_ATT2)  { src = s9;  off = i - WO_B2R; }
    else if (i < WO_BIAS2) { src = s10; off = i - WO_ATT2; }
    else                   { src = s11; off = i - WO_BIAS2; }
    dst[i] = (*flag) ? bload(src, off) : ((const float*)src)[off];
}

// ================= CSR build (counting sort by destination) =================
__global__ void k_hist(const int* __restrict__ edst, int* __restrict__ cnt) {
    int e = blockIdx.x * blockDim.x + threadIdx.x;
    if (e >= ETOT) return;
    int d = (e < N_EDGES) ? edst[e] : (e - N_EDGES);
    atomicAdd(&cnt[d], 1);
}

__global__ void k_scan1(const int* __restrict__ cnt, int* __restrict__ rp,
                        int* __restrict__ bsum) {
    __shared__ int tmp[256];
    int t = threadIdx.x, i = blockIdx.x * 256 + t;
    int v = (i < N_NODES) ? cnt[i] : 0;
    tmp[t] = v;
    __syncthreads();
    for (int off = 1; off < 256; off <<= 1) {
        int x = tmp[t];
        if (t >= off) x += tmp[t - off];
        __syncthreads();
        tmp[t] = x;
        __syncthreads();
    }
    if (i < N_NODES) rp[i] = tmp[t] - v;  // exclusive within block
    if (t == 255) bsum[blockIdx.x] = tmp[255];
}

__global__ void k_scan2(int* __restrict__ bsum, int* __restrict__ rp) {
    __shared__ int tmp[512];
    int t = threadIdx.x;
    int v = (t < NBLK) ? bsum[t] : 0;
    tmp[t] = v;
    __syncthreads();
    for (int off = 1; off < 512; off <<= 1) {
        int x = tmp[t];
        if (t >= off) x += tmp[t - off];
        __syncthreads();
        tmp[t] = x;
        __syncthreads();
    }
    if (t < NBLK) bsum[t] = tmp[t] - v;  // exclusive block offsets
    if (t == 0) rp[N_NODES] = ETOT;
}

__global__ void k_scan3(int* __restrict__ rp, const int* __restrict__ bsum,
                        int* __restrict__ cursor) {
    int i = blockIdx.x * 256 + threadIdx.x;
    if (i >= N_NODES) return;
    int v = rp[i] + bsum[blockIdx.x];
    rp[i] = v;
    cursor[i] = v;
}

__global__ void k_scatter(const int* __restrict__ esrc, const int* __restrict__ edst,
                          int* __restrict__ cursor, int* __restrict__ csr) {
    int e = blockIdx.x * blockDim.x + threadIdx.x;
    if (e >= ETOT) return;
    int s = (e < N_EDGES) ? esrc[e] : (e - N_EDGES);
    int d = (e < N_EDGES) ? edst[e] : (e - N_EDGES);
    int pos = atomicAdd(&cursor[d], 1);
    csr[pos] = s;
}

// ================= layer-1 GEMMs (fused l/r) =================
// 8 nodes per 128-thread block; x rows staged in LDS; W streamed (L2-resident).
__global__ void __launch_bounds__(128) k_gemm1(const void* __restrict__ x,
                                               const unsigned* __restrict__ flag,
                                               const float* __restrict__ wb,
                                               float* __restrict__ xl, float* __restrict__ xr) {
    __shared__ float xs[8 * NFEAT];
    const float* W1l = wb + WO_W1L;
    const float* b1l = wb + WO_B1L;
    const float* W1r = wb + WO_W1R;
    const float* b1r = wb + WO_B1R;
    int node0 = blockIdx.x * 8;
    unsigned isbf = *flag;
    for (int idx = threadIdx.x; idx < 8 * NFEAT; idx += 128) {
        int n = idx / NFEAT, k = idx - n * NFEAT;
        size_t g = (size_t)(node0 + n) * NFEAT + k;
        xs[idx] = isbf ? bload(x, g) : ((const float*)x)[g];
    }
    __syncthreads();
    int j = threadIdx.x;
    float accl[8], accr[8];
#pragma unroll
    for (int n = 0; n < 8; n++) { accl[n] = b1l[j]; accr[n] = b1r[j]; }
    for (int k = 0; k < NFEAT; k++) {
        float wl = W1l[k * HID + j];
        float wr = W1r[k * HID + j];
#pragma unroll
        for (int n = 0; n < 8; n++) {
            float xv = xs[n * NFEAT + k];
            accl[n] = fmaf(xv, wl, accl[n]);
            accr[n] = fmaf(xv, wr, accr[n]);
        }
    }
#pragma unroll
    for (int n = 0; n < 8; n++) {
        size_t o = (size_t)(node0 + n) * HID + j;
        xl[o] = accl[n];
        xr[o] = accr[n];
    }
}

// ================= fused layer-1 attention: per-dst gather, online softmax ===
// One wave per destination node. Fuses score + segment-softmax + weighted
// aggregate + bias + relu. h may alias xr: each index d is read (xr[d]) before
// written (h[d]) by exactly one wave.
__global__ void __launch_bounds__(256) k_gat1(const int* __restrict__ rowptr,
                                              const int* __restrict__ csr,
                                              const float* __restrict__ xl,
                                              const float* __restrict__ xr,
                                              const float* __restrict__ att,
                                              const float* __restrict__ bias,
                                              float* __restrict__ h) {
    int wave = threadIdx.x >> 6, lane = threadIdx.x & 63;
    int d = blockIdx.x * 4 + wave;
    if (d >= N_NODES) return;
    float xr0 = xr[(size_t)d * HID + lane];
    float xr1 = xr[(size_t)d * HID + 64 + lane];
    float at0 = att[lane], at1 = att[lane + 64];
    int beg = rowptr[d], end = rowptr[d + 1];
    float m = -INFINITY, l = 0.f, o0 = 0.f, o1 = 0.f;
    // software-pipelined row prefetch
    int s = csr[beg];
    float a0 = xl[(size_t)s * HID + lane];
    float a1 = xl[(size_t)s * HID + 64 + lane];
    for (int j = beg; j < end; j++) {
        float c0 = a0, c1 = a1;
        if (j + 1 < end) {
            int s2 = csr[j + 1];
            a0 = xl[(size_t)s2 * HID + lane];
            a1 = xl[(size_t)s2 * HID + 64 + lane];
        }
        float p = at0 * lrelu(c0 + xr0) + at1 * lrelu(c1 + xr1);
#pragma unroll
        for (int off = 1; off < 64; off <<= 1) p += __shfl_xor(p, off);
        if (p > m) {
            float sc = __expf(m - p);  // 0 when m=-inf
            l *= sc; o0 *= sc; o1 *= sc;
            m = p;
        }
        float a = __expf(p - m);
        l += a;
        o0 = fmaf(a, c0, o0);
        o1 = fmaf(a, c1, o1);
    }
    float inv = 1.f / l;  // every node has its self-loop -> l > 0
    float h0 = fmaf(o0, inv, bias[lane]);
    float h1 = fmaf(o1, inv, bias[lane + 64]);
    h[(size_t)d * HID + lane] = h0 > 0.f ? h0 : 0.f;
    h[(size_t)d * HID + 64 + lane] = h1 > 0.f ? h1 : 0.f;
}

// ================= layer-2 GEMMs: wave per node, shuffle K-reduce ============
__global__ void __launch_bounds__(256) k_gemm2(const float* __restrict__ h,
                                               const float* __restrict__ wb,
                                               float* __restrict__ xl2, float* __restrict__ xr2) {
    const float* W2l = wb + WO_W2L;
    const float* b2l = wb + WO_B2L;
    const float* W2r = wb + WO_W2R;
    const float* b2r = wb + WO_B2R;
    int wave = threadIdx.x >> 6, lane = threadIdx.x & 63;
    int node = blockIdx.x * 4 + wave;
    if (node >= N_NODES) return;
    const float* hr = h + (size_t)node * HID;
    float h0 = hr[lane], h1 = hr[lane + 64];
    float al0 = h0 * W2l[lane * 2 + 0] + h1 * W2l[(lane + 64) * 2 + 0];
    float al1 = h0 * W2l[lane * 2 + 1] + h1 * W2l[(lane + 64) * 2 + 1];
    float ar0 = h0 * W2r[lane * 2 + 0] + h1 * W2r[(lane + 64) * 2 + 0];
    float ar1 = h0 * W2r[lane * 2 + 1] + h1 * W2r[(lane + 64) * 2 + 1];
#pragma unroll
    for (int off = 32; off > 0; off >>= 1) {
        al0 += __shfl_down(al0, off);
        al1 += __shfl_down(al1, off);
        ar0 += __shfl_down(ar0, off);
        ar1 += __shfl_down(ar1, off);
    }
    if (lane == 0) {
        xl2[node * 2 + 0] = al0 + b2l[0];
        xl2[node * 2 + 1] = al1 + b2l[1];
        xr2[node * 2 + 0] = ar0 + b2r[0];
        xr2[node * 2 + 1] = ar1 + b2r[1];
    }
}

// ================= fused layer-2 attention: thread per dst node ==============
__global__ void __launch_bounds__(256) k_gat2(const int* __restrict__ rowptr,
                                              const int* __restrict__ csr,
                                              const float* __restrict__ xl2,
                                              const float* __restrict__ xr2,
                                              const float* __restrict__ wb,
                                              const unsigned* __restrict__ flag,
                                              void* __restrict__ dout) {
    int d = blockIdx.x * 256 + threadIdx.x;
    if (d >= N_NODES) return;
    float xr0 = xr2[d * 2 + 0], xr1 = xr2[d * 2 + 1];
    float at0 = wb[WO_ATT2], at1 = wb[WO_ATT2 + 1];
    int beg = rowptr[d], end = rowptr[d + 1];
    float m = -INFINITY, l = 0.f, o0 = 0.f, o1 = 0.f;
    for (int j = beg; j < end; j++) {
        int s = csr[j];
        float b0 = xl2[s * 2 + 0], b1 = xl2[s * 2 + 1];
        float p = at0 * lrelu(b0 + xr0) + at1 * lrelu(b1 + xr1);
        if (p > m) {
            float sc = __expf(m - p);
            l *= sc; o0 *= sc; o1 *= sc;
            m = p;
        }
        float a = __expf(p - m);
        l += a;
        o0 = fmaf(a, b0, o0);
        o1 = fmaf(a, b1, o1);
    }
    float inv = 1.f / l;
    float v0 = fmaf(o0, inv, wb[WO_BIAS2 + 0]);
    float v1 = fmaf(o1, inv, wb[WO_BIAS2 + 1]);
    if (*flag) {
        ((__hip_bfloat16*)dout)[d * 2 + 0] = __float2bfloat16(v0);
        ((__hip_bfloat16*)dout)[d * 2 + 1] = __float2bfloat16(v1);
    } else {
        ((float*)dout)[d * 2 + 0] = v0;
        ((float*)dout)[d * 2 + 1] = v1;
    }
}

extern "C" void kernel_launch(void* const* d_in, const int* in_sizes, int n_in,
                              void* d_out, int out_size, void* d_ws, size_t ws_size,
                              hipStream_t stream) {
    char* w = (char*)d_ws;
    unsigned* flag = (unsigned*)(w + (size_t)OFF_FLAG * 4);
    float* wb = (float*)(w + (size_t)OFF_W * 4);
    float* xl1 = (float*)(w + (size_t)OFF_XL1 * 4);
    float* xr1 = (float*)(w + (size_t)OFF_XR1 * 4);  // reused as h
    int* csr = (int*)(w + (size_t)OFF_CSR * 4);
    int* rowptr = (int*)(w + (size_t)OFF_ROWPTR * 4);
    int* cursor = (int*)(w + (size_t)OFF_CURSOR * 4);  // counts, then cursor
    int* bsum = (int*)(w + (size_t)OFF_BSUM * 4);
    float* xl2 = (float*)(w + (size_t)OFF_XL2 * 4);
    float* xr2 = (float*)(w + (size_t)OFF_XR2 * 4);
    const int* esrc = (const int*)d_in[1];
    const int* edst = (const int*)d_in[2];

    k_detect<<<1, 256, 0, stream>>>((const unsigned short*)d_in[0], flag);
    k_cvt_w<<<(W_TOTAL + 255) / 256, 256, 0, stream>>>(flag,
        d_in[3], d_in[4], d_in[5], d_in[6], d_in[7], d_in[8],
        d_in[9], d_in[10], d_in[11], d_in[12], d_in[13], d_in[14], wb);

    // ---- CSR build (shared by both layers) ----
    hipMemsetAsync(cursor, 0, (size_t)N_NODES * 4, stream);
    k_hist<<<(ETOT + 255) / 256, 256, 0, stream>>>(edst, cursor);
    k_scan1<<<NBLK, 256, 0, stream>>>(cursor, rowptr, bsum);
    k_scan2<<<1, 512, 0, stream>>>(bsum, rowptr);
    k_scan3<<<NBLK, 256, 0, stream>>>(rowptr, bsum, cursor);
    k_scatter<<<(ETOT + 255) / 256, 256, 0, stream>>>(esrc, edst, cursor, csr);

    // ---- layer 1 ----
    k_gemm1<<<N_NODES / 8, 128, 0, stream>>>(d_in[0], flag, wb, xl1, xr1);
    k_gat1<<<(N_NODES + 3) / 4, 256, 0, stream>>>(rowptr, csr, xl1, xr1,
                                                  wb + WO_ATT1, wb + WO_BIAS1, xr1);

    // ---- layer 2 ----
    k_gemm2<<<(N_NODES + 3) / 4, 256, 0, stream>>>(xr1, wb, xl2, xr2);
    k_gat2<<<(N_NODES + 255) / 256, 256, 0, stream>>>(rowptr, csr, xl2, xr2,
                                                      wb, flag, d_out);
}

// Round 3
// 621.329 us; speedup vs baseline: 2.8713x; 1.1961x over previous
//
#include <hip/hip_runtime.h>
#include <hip/hip_bf16.h>

#define N_NODES 100000
#define N_EDGES 1600000
#define ETOT (N_EDGES + N_NODES)
#define NFEAT 165
#define HID 128
#define NCLS 2
#define NEG 0.2f
#define NBLK 391  // ceil(N_NODES/256)

// ---- workspace layout (units of 4 bytes) ----
#define OFF_FLAG 0
#define OFF_W 16
// weight sub-offsets (within wb = ws + OFF_W)
#define WO_W1L 0
#define WO_B1L 21120
#define WO_W1R 21248
#define WO_B1R 42368
#define WO_ATT1 42496
#define WO_BIAS1 42624
#define WO_W2L 42752
#define WO_B2L 43008
#define WO_W2R 43010
#define WO_B2R 43266
#define WO_ATT2 43268
#define WO_BIAS2 43270
#define W_TOTAL 43272

#define OFF_XLB 43392                       // bf16 xl rows [N][128] (6.4M words)
#define OFF_XRB (OFF_XLB + 6400000)         // bf16 xr rows
#define OFF_H   (OFF_XRB + 6400000)         // fp32 h [N][128]
#define OFF_CSR (OFF_H + N_NODES * HID)     // csr_src[ETOT]
#define OFF_ROWPTR (OFF_CSR + ETOT)
#define OFF_CURSOR (OFF_ROWPTR + N_NODES + 8)
#define OFF_BSUM (OFF_CURSOR + N_NODES)
#define OFF_XL2 (OFF_BSUM + 1024)
#define OFF_XR2 (OFF_XL2 + N_NODES * NCLS)

__device__ __forceinline__ float bload(const void* p, size_t i) {
    unsigned u = ((const unsigned short*)p)[i];
    return __uint_as_float(u << 16);
}

// lrelu(v) = 0.6v + 0.4|v|  (abs folds into the fma as an input modifier)
__device__ __forceinline__ float lrelu(float v) {
    return fmaf(0.4f, fabsf(v), 0.6f * v);
}

__device__ __forceinline__ void unpack8(uint4 q, float* f) {
    f[0] = __uint_as_float(q.x << 16); f[1] = __uint_as_float(q.x & 0xffff0000u);
    f[2] = __uint_as_float(q.y << 16); f[3] = __uint_as_float(q.y & 0xffff0000u);
    f[4] = __uint_as_float(q.z << 16); f[5] = __uint_as_float(q.z & 0xffff0000u);
    f[6] = __uint_as_float(q.w << 16); f[7] = __uint_as_float(q.w & 0xffff0000u);
}

// ---- dtype detection: are the float tensors bf16-packed or fp32? ----
__global__ void k_detect(const unsigned short* __restrict__ x16, unsigned* flag) {
    __shared__ int cnt;
    if (threadIdx.x == 0) cnt = 0;
    __syncthreads();
    int c = 0;
    for (int t = 0; t < 2; t++) {
        unsigned short h = x16[threadIdx.x * 2 + t];
        unsigned e = (h >> 7) & 0xFF;
        if ((h & 0x7FFF) == 0 || (e >= 100 && e <= 140)) c++;
    }
    atomicAdd(&cnt, c);
    __syncthreads();
    if (threadIdx.x == 0) *flag = (cnt >= 384) ? 1u : 0u;
}

// ---- convert all weight tensors to fp32 in workspace ----
__global__ void k_cvt_w(const unsigned* __restrict__ flag,
                        const void* s0, const void* s1, const void* s2, const void* s3,
                        const void* s4, const void* s5, const void* s6, const void* s7,
                        const void* s8, const void* s9, const void* s10, const void* s11,
                        float* __restrict__ dst) {
    int i = blockIdx.x * blockDim.x + threadIdx.x;
    if (i >= W_TOTAL) return;
    const void* src; int off;
    if      (i < WO_B1L)   { src = s0;  off = i; }
    else if (i < WO_W1R)   { src = s1;  off = i - WO_B1L; }
    else if (i < WO_B1R)   { src = s2;  off = i - WO_W1R; }
    else if (i < WO_ATT1)  { src = s3;  off = i - WO_B1R; }
    else if (i < WO_BIAS1) { src = s4;  off = i - WO_ATT1; }
    else if (i < WO_W2L)   { src = s5;  off = i - WO_BIAS1; }
    else if (i < WO_B2L)   { src = s6;  off = i - WO_W2L; }
    else if (i < WO_W2R)   { src = s7;  off = i - WO_B2L; }
    else if (i < WO_B2R)   { src = s8;  off = i - WO_W2R; }
    else if (i < WO_ATT2)  { src = s9;  off = i - WO_B2R; }
    else if (i < WO_BIAS2) { src = s10; off = i - WO_ATT2; }
    else                   { src = s11; off = i - WO_BIAS2; }
    dst[i] = (*flag) ? bload(src, off) : ((const float*)src)[off];
}

// ================= CSR build (counting sort by destination) =================
__global__ void k_hist(const int* __restrict__ edst, int* __restrict__ cnt) {
    int e = blockIdx.x * blockDim.x + threadIdx.x;
    if (e >= ETOT) return;
    int d = (e < N_EDGES) ? edst[e] : (e - N_EDGES);
    atomicAdd(&cnt[d], 1);
}

__global__ void k_scan1(const int* __restrict__ cnt, int* __restrict__ rp,
                        int* __restrict__ bsum) {
    __shared__ int tmp[256];
    int t = threadIdx.x, i = blockIdx.x * 256 + t;
    int v = (i < N_NODES) ? cnt[i] : 0;
    tmp[t] = v;
    __syncthreads();
    for (int off = 1; off < 256; off <<= 1) {
        int x = tmp[t];
        if (t >= off) x += tmp[t - off];
        __syncthreads();
        tmp[t] = x;
        __syncthreads();
    }
    if (i < N_NODES) rp[i] = tmp[t] - v;
    if (t == 255) bsum[blockIdx.x] = tmp[255];
}

__global__ void k_scan2(int* __restrict__ bsum, int* __restrict__ rp) {
    __shared__ int tmp[512];
    int t = threadIdx.x;
    int v = (t < NBLK) ? bsum[t] : 0;
    tmp[t] = v;
    __syncthreads();
    for (int off = 1; off < 512; off <<= 1) {
        int x = tmp[t];
        if (t >= off) x += tmp[t - off];
        __syncthreads();
        tmp[t] = x;
        __syncthreads();
    }
    if (t < NBLK) bsum[t] = tmp[t] - v;
    if (t == 0) rp[N_NODES] = ETOT;
}

__global__ void k_scan3(int* __restrict__ rp, const int* __restrict__ bsum,
                        int* __restrict__ cursor) {
    int i = blockIdx.x * 256 + threadIdx.x;
    if (i >= N_NODES) return;
    int v = rp[i] + bsum[blockIdx.x];
    rp[i] = v;
    cursor[i] = v;
}

__global__ void k_scatter(const int* __restrict__ esrc, const int* __restrict__ edst,
                          int* __restrict__ cursor, int* __restrict__ csr) {
    int e = blockIdx.x * blockDim.x + threadIdx.x;
    if (e >= ETOT) return;
    int s = (e < N_EDGES) ? esrc[e] : (e - N_EDGES);
    int d = (e < N_EDGES) ? edst[e] : (e - N_EDGES);
    int pos = atomicAdd(&cursor[d], 1);
    csr[pos] = s;
}

// ================= layer-1 GEMMs (fused l/r), bf16 output =================
// 16 nodes per 128-thread block; x rows staged in LDS (float4 reads);
// W streamed from L2 (1.05 GB total).
__global__ void __launch_bounds__(128) k_gemm1(const void* __restrict__ x,
                                               const unsigned* __restrict__ flag,
                                               const float* __restrict__ wb,
                                               __hip_bfloat16* __restrict__ xlb,
                                               __hip_bfloat16* __restrict__ xrb) {
    __shared__ float xs[16 * 168];
    const float* W1l = wb + WO_W1L;
    const float* b1l = wb + WO_B1L;
    const float* W1r = wb + WO_W1R;
    const float* b1r = wb + WO_B1R;
    int node0 = blockIdx.x * 16;
    unsigned isbf = *flag;
    for (int idx = threadIdx.x; idx < 16 * NFEAT; idx += 128) {
        int n = idx / NFEAT, k = idx - n * NFEAT;
        size_t g = (size_t)(node0 + n) * NFEAT + k;
        xs[n * 168 + k] = isbf ? bload(x, g) : ((const float*)x)[g];
    }
    __syncthreads();
    int j = threadIdx.x;
    float accl[16], accr[16];
#pragma unroll
    for (int n = 0; n < 16; n++) { accl[n] = b1l[j]; accr[n] = b1r[j]; }
    for (int k4 = 0; k4 < NFEAT - 1; k4 += 4) {
        float wl0 = W1l[(k4 + 0) * HID + j], wr0 = W1r[(k4 + 0) * HID + j];
        float wl1 = W1l[(k4 + 1) * HID + j], wr1 = W1r[(k4 + 1) * HID + j];
        float wl2 = W1l[(k4 + 2) * HID + j], wr2 = W1r[(k4 + 2) * HID + j];
        float wl3 = W1l[(k4 + 3) * HID + j], wr3 = W1r[(k4 + 3) * HID + j];
#pragma unroll
        for (int n = 0; n < 16; n++) {
            float4 xv = *(const float4*)&xs[n * 168 + k4];
            accl[n] = fmaf(xv.x, wl0, accl[n]);
            accr[n] = fmaf(xv.x, wr0, accr[n]);
            accl[n] = fmaf(xv.y, wl1, accl[n]);
            accr[n] = fmaf(xv.y, wr1, accr[n]);
            accl[n] = fmaf(xv.z, wl2, accl[n]);
            accr[n] = fmaf(xv.z, wr2, accr[n]);
            accl[n] = fmaf(xv.w, wl3, accl[n]);
            accr[n] = fmaf(xv.w, wr3, accr[n]);
        }
    }
    {   // k = 164 tail
        float wl = W1l[164 * HID + j], wr = W1r[164 * HID + j];
#pragma unroll
        for (int n = 0; n < 16; n++) {
            float xv = xs[n * 168 + 164];
            accl[n] = fmaf(xv, wl, accl[n]);
            accr[n] = fmaf(xv, wr, accr[n]);
        }
    }
#pragma unroll
    for (int n = 0; n < 16; n++) {
        size_t o = (size_t)(node0 + n) * HID + j;
        xlb[o] = __float2bfloat16(accl[n]);
        xrb[o] = __float2bfloat16(accr[n]);
    }
}

// ================= fused layer-1 attention =================
// One wave per destination node; 4 edges in flight (16 lanes each, 8 dims/lane).
// Softmax without max-subtraction (scores are O(1); exp(p)/sum identical).
__global__ void __launch_bounds__(256) k_gat1(const int* __restrict__ rowptr,
                                              const int* __restrict__ csr,
                                              const __hip_bfloat16* __restrict__ xlb,
                                              const __hip_bfloat16* __restrict__ xrb,
                                              const float* __restrict__ att,
                                              const float* __restrict__ bias,
                                              float* __restrict__ h) {
    int wave = threadIdx.x >> 6, lane = threadIdx.x & 63;
    int d = blockIdx.x * 4 + wave;
    if (d >= N_NODES) return;
    int sub = lane >> 4, li = lane & 15;

    uint4 qr = ((const uint4*)(xrb + (size_t)d * HID))[li];
    float xrv[8]; unpack8(qr, xrv);
    float atv[8];
    {
        float4 t0 = ((const float4*)att)[li * 2];
        float4 t1 = ((const float4*)att)[li * 2 + 1];
        atv[0] = t0.x; atv[1] = t0.y; atv[2] = t0.z; atv[3] = t0.w;
        atv[4] = t1.x; atv[5] = t1.y; atv[6] = t1.z; atv[7] = t1.w;
    }
    int beg = rowptr[d], end = rowptr[d + 1];
    int iters = (end - beg + 3) >> 2;
    float l = 0.f, o[8];
#pragma unroll
    for (int t = 0; t < 8; t++) o[t] = 0.f;

    int j = beg + sub;
    bool valid = j < end;
    int s = valid ? csr[j] : 0;
    uint4 q = *(const uint4*)(xlb + (size_t)s * HID + li * 8);

    for (int it = 0; it < iters; it++) {
        float c[8]; unpack8(q, c);
        bool v = valid;
        // prefetch next edge's row
        j += 4;
        valid = j < end;
        int sn = valid ? csr[j] : 0;
        q = *(const uint4*)(xlb + (size_t)sn * HID + li * 8);

        float p = 0.f;
#pragma unroll
        for (int t = 0; t < 8; t++) p = fmaf(atv[t], lrelu(c[t] + xrv[t]), p);
        p += __shfl_xor(p, 1);
        p += __shfl_xor(p, 2);
        p += __shfl_xor(p, 4);
        p += __shfl_xor(p, 8);
        float a = v ? __expf(p) : 0.f;
        l += a;
#pragma unroll
        for (int t = 0; t < 8; t++) o[t] = fmaf(a, c[t], o[t]);
    }
    // merge the 4 subgroups
    l += __shfl_xor(l, 16);
    l += __shfl_xor(l, 32);
#pragma unroll
    for (int t = 0; t < 8; t++) {
        o[t] += __shfl_xor(o[t], 16);
        o[t] += __shfl_xor(o[t], 32);
    }
    if (sub == 0) {
        float inv = 1.f / l;  // self-loop guarantees l > 0
        float4 bv0 = ((const float4*)bias)[li * 2];
        float4 bv1 = ((const float4*)bias)[li * 2 + 1];
        float4 r0, r1;
        r0.x = fmaf(o[0], inv, bv0.x); r0.y = fmaf(o[1], inv, bv0.y);
        r0.z = fmaf(o[2], inv, bv0.z); r0.w = fmaf(o[3], inv, bv0.w);
        r1.x = fmaf(o[4], inv, bv1.x); r1.y = fmaf(o[5], inv, bv1.y);
        r1.z = fmaf(o[6], inv, bv1.z); r1.w = fmaf(o[7], inv, bv1.w);
        r0.x = fmaxf(r0.x, 0.f); r0.y = fmaxf(r0.y, 0.f);
        r0.z = fmaxf(r0.z, 0.f); r0.w = fmaxf(r0.w, 0.f);
        r1.x = fmaxf(r1.x, 0.f); r1.y = fmaxf(r1.y, 0.f);
        r1.z = fmaxf(r1.z, 0.f); r1.w = fmaxf(r1.w, 0.f);
        float4* hp = (float4*)(h + (size_t)d * HID + li * 8);
        hp[0] = r0;
        hp[1] = r1;
    }
}

// ================= layer-2 GEMMs: wave per node, shuffle K-reduce ============
__global__ void __launch_bounds__(256) k_gemm2(const float* __restrict__ h,
                                               const float* __restrict__ wb,
                                               float* __restrict__ xl2, float* __restrict__ xr2) {
    const float* W2l = wb + WO_W2L;
    const float* b2l = wb + WO_B2L;
    const float* W2r = wb + WO_W2R;
    const float* b2r = wb + WO_B2R;
    int wave = threadIdx.x >> 6, lane = threadIdx.x & 63;
    int node = blockIdx.x * 4 + wave;
    if (node >= N_NODES) return;
    const float* hr = h + (size_t)node * HID;
    float h0 = hr[lane], h1 = hr[lane + 64];
    float al0 = h0 * W2l[lane * 2 + 0] + h1 * W2l[(lane + 64) * 2 + 0];
    float al1 = h0 * W2l[lane * 2 + 1] + h1 * W2l[(lane + 64) * 2 + 1];
    float ar0 = h0 * W2r[lane * 2 + 0] + h1 * W2r[(lane + 64) * 2 + 0];
    float ar1 = h0 * W2r[lane * 2 + 1] + h1 * W2r[(lane + 64) * 2 + 1];
#pragma unroll
    for (int off = 32; off > 0; off >>= 1) {
        al0 += __shfl_down(al0, off);
        al1 += __shfl_down(al1, off);
        ar0 += __shfl_down(ar0, off);
        ar1 += __shfl_down(ar1, off);
    }
    if (lane == 0) {
        xl2[node * 2 + 0] = al0 + b2l[0];
        xl2[node * 2 + 1] = al1 + b2l[1];
        xr2[node * 2 + 0] = ar0 + b2r[0];
        xr2[node * 2 + 1] = ar1 + b2r[1];
    }
}

// ================= fused layer-2 attention: thread per dst node ==============
__global__ void __launch_bounds__(256) k_gat2(const int* __restrict__ rowptr,
                                              const int* __restrict__ csr,
                                              const float* __restrict__ xl2,
                                              const float* __restrict__ xr2,
                                              const float* __restrict__ wb,
                                              const unsigned* __restrict__ flag,
                                              void* __restrict__ dout) {
    int d = blockIdx.x * 256 + threadIdx.x;
    if (d >= N_NODES) return;
    float xr0 = xr2[d * 2 + 0], xr1 = xr2[d * 2 + 1];
    float at0 = wb[WO_ATT2], at1 = wb[WO_ATT2 + 1];
    int beg = rowptr[d], end = rowptr[d + 1];
    float l = 0.f, o0 = 0.f, o1 = 0.f;
    for (int j = beg; j < end; j++) {
        int s = csr[j];
        float b0 = xl2[s * 2 + 0], b1 = xl2[s * 2 + 1];
        float p = at0 * lrelu(b0 + xr0) + at1 * lrelu(b1 + xr1);
        float a = __expf(p);
        l += a;
        o0 = fmaf(a, b0, o0);
        o1 = fmaf(a, b1, o1);
    }
    float inv = 1.f / l;
    float v0 = fmaf(o0, inv, wb[WO_BIAS2 + 0]);
    float v1 = fmaf(o1, inv, wb[WO_BIAS2 + 1]);
    if (*flag) {
        ((__hip_bfloat16*)dout)[d * 2 + 0] = __float2bfloat16(v0);
        ((__hip_bfloat16*)dout)[d * 2 + 1] = __float2bfloat16(v1);
    } else {
        ((float*)dout)[d * 2 + 0] = v0;
        ((float*)dout)[d * 2 + 1] = v1;
    }
}

extern "C" void kernel_launch(void* const* d_in, const int* in_sizes, int n_in,
                              void* d_out, int out_size, void* d_ws, size_t ws_size,
                              hipStream_t stream) {
    char* w = (char*)d_ws;
    unsigned* flag = (unsigned*)(w + (size_t)OFF_FLAG * 4);
    float* wb = (float*)(w + (size_t)OFF_W * 4);
    __hip_bfloat16* xlb = (__hip_bfloat16*)(w + (size_t)OFF_XLB * 4);
    __hip_bfloat16* xrb = (__hip_bfloat16*)(w + (size_t)OFF_XRB * 4);
    float* h = (float*)(w + (size_t)OFF_H * 4);
    int* csr = (int*)(w + (size_t)OFF_CSR * 4);
    int* rowptr = (int*)(w + (size_t)OFF_ROWPTR * 4);
    int* cursor = (int*)(w + (size_t)OFF_CURSOR * 4);
    int* bsum = (int*)(w + (size_t)OFF_BSUM * 4);
    float* xl2 = (float*)(w + (size_t)OFF_XL2 * 4);
    float* xr2 = (float*)(w + (size_t)OFF_XR2 * 4);
    const int* esrc = (const int*)d_in[1];
    const int* edst = (const int*)d_in[2];

    k_detect<<<1, 256, 0, stream>>>((const unsigned short*)d_in[0], flag);
    k_cvt_w<<<(W_TOTAL + 255) / 256, 256, 0, stream>>>(flag,
        d_in[3], d_in[4], d_in[5], d_in[6], d_in[7], d_in[8],
        d_in[9], d_in[10], d_in[11], d_in[12], d_in[13], d_in[14], wb);

    // ---- CSR build (shared by both layers) ----
    hipMemsetAsync(cursor, 0, (size_t)N_NODES * 4, stream);
    k_hist<<<(ETOT + 255) / 256, 256, 0, stream>>>(edst, cursor);
    k_scan1<<<NBLK, 256, 0, stream>>>(cursor, rowptr, bsum);
    k_scan2<<<1, 512, 0, stream>>>(bsum, rowptr);
    k_scan3<<<NBLK, 256, 0, stream>>>(rowptr, bsum, cursor);
    k_scatter<<<(ETOT + 255) / 256, 256, 0, stream>>>(esrc, edst, cursor, csr);

    // ---- layer 1 ----
    k_gemm1<<<N_NODES / 16, 128, 0, stream>>>(d_in[0], flag, wb, xlb, xrb);
    k_gat1<<<(N_NODES + 3) / 4, 256, 0, stream>>>(rowptr, csr, xlb, xrb,
                                                  wb + WO_ATT1, wb + WO_BIAS1, h);

    // ---- layer 2 ----
    k_gemm2<<<(N_NODES + 3) / 4, 256, 0, stream>>>(h, wb, xl2, xr2);
    k_gat2<<<(N_NODES + 255) / 256, 256, 0, stream>>>(rowptr, csr, xl2, xr2,
                                                      wb, flag, d_out);
}

// Round 4
// 510.034 us; speedup vs baseline: 3.4979x; 1.2182x over previous
//
#include <hip/hip_runtime.h>
#include <hip/hip_bf16.h>

#define N_NODES 100000
#define NPAD 100032                         // 64-row-aligned node count
#define N_EDGES 1600000
#define ETOT (N_EDGES + N_NODES)
#define NFEAT 165
#define KP 192                              // K padded to 32-multiple
#define HID 128
#define NCLS 2
#define NEG 0.2f
#define NBLK 391  // ceil(N_NODES/256)

typedef short bf16x8 __attribute__((ext_vector_type(8)));
typedef float f32x4 __attribute__((ext_vector_type(4)));

// ---- workspace layout (units of 4 bytes) ----
#define OFF_FLAG 0
#define OFF_W 16
// weight sub-offsets (within wb = ws + OFF_W)
#define WO_W1L 0
#define WO_B1L 21120
#define WO_W1R 21248
#define WO_B1R 42368
#define WO_ATT1 42496
#define WO_BIAS1 42624
#define WO_W2L 42752
#define WO_B2L 43008
#define WO_W2R 43010
#define WO_B2R 43266
#define WO_ATT2 43268
#define WO_BIAS2 43270
#define W_TOTAL 43272

#define OFF_XB   43392                      // bf16 x padded [NPAD][192] (9.6M words)
#define OFF_WT   (OFF_XB + NPAD * KP / 2)   // bf16 WT [256][192]
#define OFF_BCAT (OFF_WT + 256 * KP / 2)    // fp32 bias concat [256]
#define OFF_XLB  (OFF_BCAT + 256)           // bf16 xl rows [NPAD][128]
#define OFF_XRB  (OFF_XLB + NPAD * HID / 2) // bf16 xr rows
#define OFF_H    (OFF_XRB + NPAD * HID / 2) // fp32 h [N][128]
#define OFF_CSR  (OFF_H + N_NODES * HID)    // csr_src[ETOT]
#define OFF_ROWPTR (OFF_CSR + ETOT)
#define OFF_CURSOR (OFF_ROWPTR + N_NODES + 8)
#define OFF_BSUM (OFF_CURSOR + N_NODES)
#define OFF_XL2 (OFF_BSUM + 1024)
#define OFF_XR2 (OFF_XL2 + N_NODES * NCLS)

__device__ __forceinline__ float bload(const void* p, size_t i) {
    unsigned u = ((const unsigned short*)p)[i];
    return __uint_as_float(u << 16);
}

// lrelu(v) = 0.6v + 0.4|v|
__device__ __forceinline__ float lrelu(float v) {
    return fmaf(0.4f, fabsf(v), 0.6f * v);
}

__device__ __forceinline__ void unpack8(uint4 q, float* f) {
    f[0] = __uint_as_float(q.x << 16); f[1] = __uint_as_float(q.x & 0xffff0000u);
    f[2] = __uint_as_float(q.y << 16); f[3] = __uint_as_float(q.y & 0xffff0000u);
    f[4] = __uint_as_float(q.z << 16); f[5] = __uint_as_float(q.z & 0xffff0000u);
    f[6] = __uint_as_float(q.w << 16); f[7] = __uint_as_float(q.w & 0xffff0000u);
}

__device__ __forceinline__ unsigned short f2b(float f) {
    __hip_bfloat16 b = __float2bfloat16(f);
    return *(unsigned short*)&b;
}

// ---- dtype detection ----
__global__ void k_detect(const unsigned short* __restrict__ x16, unsigned* flag) {
    __shared__ int cnt;
    if (threadIdx.x == 0) cnt = 0;
    __syncthreads();
    int c = 0;
    for (int t = 0; t < 2; t++) {
        unsigned short h = x16[threadIdx.x * 2 + t];
        unsigned e = (h >> 7) & 0xFF;
        if ((h & 0x7FFF) == 0 || (e >= 100 && e <= 140)) c++;
    }
    atomicAdd(&cnt, c);
    __syncthreads();
    if (threadIdx.x == 0) *flag = (cnt >= 384) ? 1u : 0u;
}

// ---- convert all weight tensors to fp32 in workspace ----
__global__ void k_cvt_w(const unsigned* __restrict__ flag,
                        const void* s0, const void* s1, const void* s2, const void* s3,
                        const void* s4, const void* s5, const void* s6, const void* s7,
                        const void* s8, const void* s9, const void* s10, const void* s11,
                        float* __restrict__ dst) {
    int i = blockIdx.x * blockDim.x + threadIdx.x;
    if (i >= W_TOTAL) return;
    const void* src; int off;
    if      (i < WO_B1L)   { src = s0;  off = i; }
    else if (i < WO_W1R)   { src = s1;  off = i - WO_B1L; }
    else if (i < WO_B1R)   { src = s2;  off = i - WO_W1R; }
    else if (i < WO_ATT1)  { src = s3;  off = i - WO_B1R; }
    else if (i < WO_BIAS1) { src = s4;  off = i - WO_ATT1; }
    else if (i < WO_W2L)   { src = s5;  off = i - WO_BIAS1; }
    else if (i < WO_B2L)   { src = s6;  off = i - WO_W2L; }
    else if (i < WO_W2R)   { src = s7;  off = i - WO_B2L; }
    else if (i < WO_B2R)   { src = s8;  off = i - WO_W2R; }
    else if (i < WO_ATT2)  { src = s9;  off = i - WO_B2R; }
    else if (i < WO_BIAS2) { src = s10; off = i - WO_ATT2; }
    else                   { src = s11; off = i - WO_BIAS2; }
    dst[i] = (*flag) ? bload(src, off) : ((const float*)src)[off];
}

// ---- x -> bf16, K padded to 192, rows padded to NPAD ----
__global__ void k_cvt_x(const void* __restrict__ x, const unsigned* __restrict__ flag,
                        unsigned short* __restrict__ xb) {
    int i = blockIdx.x * 256 + threadIdx.x;
    if (i >= NPAD * KP) return;
    int row = i / KP, col = i - row * KP;
    unsigned short v = 0;
    if (row < N_NODES && col < NFEAT) {
        size_t g = (size_t)row * NFEAT + col;
        if (*flag) v = ((const unsigned short*)x)[g];
        else       v = f2b(((const float*)x)[g]);
    }
    xb[i] = v;
}

// ---- pack W1l|W1r transposed to bf16 WT[256][192] + bias concat ----
__global__ void k_cvt_wt(const float* __restrict__ wb, unsigned short* __restrict__ wt,
                         float* __restrict__ bcat) {
    int i = blockIdx.x * 256 + threadIdx.x;
    if (i >= 256 * KP) return;
    int n = i / KP, k = i - n * KP;
    float f = 0.f;
    if (k < NFEAT)
        f = (n < HID) ? wb[WO_W1L + k * HID + n] : wb[WO_W1R + k * HID + (n - HID)];
    wt[i] = f2b(f);
    if (k == 0) bcat[n] = (n < HID) ? wb[WO_B1L + n] : wb[WO_B1R + (n - HID)];
}

// ================= CSR build (counting sort by destination) =================
__global__ void k_hist(const int* __restrict__ edst, int* __restrict__ cnt) {
    int e = blockIdx.x * blockDim.x + threadIdx.x;
    if (e >= ETOT) return;
    int d = (e < N_EDGES) ? edst[e] : (e - N_EDGES);
    atomicAdd(&cnt[d], 1);
}

__global__ void k_scan1(const int* __restrict__ cnt, int* __restrict__ rp,
                        int* __restrict__ bsum) {
    __shared__ int tmp[256];
    int t = threadIdx.x, i = blockIdx.x * 256 + t;
    int v = (i < N_NODES) ? cnt[i] : 0;
    tmp[t] = v;
    __syncthreads();
    for (int off = 1; off < 256; off <<= 1) {
        int x = tmp[t];
        if (t >= off) x += tmp[t - off];
        __syncthreads();
        tmp[t] = x;
        __syncthreads();
    }
    if (i < N_NODES) rp[i] = tmp[t] - v;
    if (t == 255) bsum[blockIdx.x] = tmp[255];
}

__global__ void k_scan2(int* __restrict__ bsum, int* __restrict__ rp) {
    __shared__ int tmp[512];
    int t = threadIdx.x;
    int v = (t < NBLK) ? bsum[t] : 0;
    tmp[t] = v;
    __syncthreads();
    for (int off = 1; off < 512; off <<= 1) {
        int x = tmp[t];
        if (t >= off) x += tmp[t - off];
        __syncthreads();
        tmp[t] = x;
        __syncthreads();
    }
    if (t < NBLK) bsum[t] = tmp[t] - v;
    if (t == 0) rp[N_NODES] = ETOT;
}

__global__ void k_scan3(int* __restrict__ rp, const int* __restrict__ bsum,
                        int* __restrict__ cursor) {
    int i = blockIdx.x * 256 + threadIdx.x;
    if (i >= N_NODES) return;
    int v = rp[i] + bsum[blockIdx.x];
    rp[i] = v;
    cursor[i] = v;
}

__global__ void k_scatter(const int* __restrict__ esrc, const int* __restrict__ edst,
                          int* __restrict__ cursor, int* __restrict__ csr) {
    int e = blockIdx.x * blockDim.x + threadIdx.x;
    if (e >= ETOT) return;
    int s = (e < N_EDGES) ? esrc[e] : (e - N_EDGES);
    int d = (e < N_EDGES) ? edst[e] : (e - N_EDGES);
    int pos = atomicAdd(&cursor[d], 1);
    csr[pos] = s;
}

// ================= layer-1 GEMM via bf16 MFMA =================
// C[NPAD][256] = xb[NPAD][192] @ WT^T; cols 0-127 -> xlb, 128-255 -> xrb.
// 64 nodes/block, 4 waves; wave w owns cols [w*64, w*64+64).
// B fragments (24/wave) held in registers; A staged in LDS.
// mfma_f32_16x16x32_bf16 layouts (m89/m91/m120-verified):
//   A: lane holds A[m=lane&15][k=(lane>>4)*8+j]
//   B: lane holds B[k=(lane>>4)*8+j][n=lane&15]
//   D: lane holds D[m=(lane>>4)*4+r][n=lane&15]
#define XS_STRIDE 200  // halves; 400 B = 16 B-aligned, li*100 words -> 2-way banks (free)
__global__ void __launch_bounds__(256) k_gemm1_mfma(
        const unsigned short* __restrict__ xb,
        const unsigned short* __restrict__ wt,
        const float* __restrict__ bcat,
        __hip_bfloat16* __restrict__ xlb,
        __hip_bfloat16* __restrict__ xrb) {
    __shared__ unsigned short xs[64 * XS_STRIDE];  // 25.6 KB
    int tid = threadIdx.x;
    int wave = tid >> 6, lane = tid & 63;
    int sub = lane >> 4, li = lane & 15;
    int node0 = blockIdx.x * 64;

    // stage 64 x-rows (64*24 chunks of 8 halves)
    for (int c = tid; c < 64 * 24; c += 256) {
        int r = c / 24, off = (c - r * 24) * 8;
        *(uint4*)&xs[r * XS_STRIDE + off] =
            *(const uint4*)&xb[(size_t)(node0 + r) * KP + off];
    }

    // B fragments: 4 n-tiles x 6 k-steps, 16 B each from WT (L2-resident)
    bf16x8 bfrag[4][6];
#pragma unroll
    for (int q = 0; q < 4; q++) {
        int n = wave * 64 + q * 16 + li;
#pragma unroll
        for (int kk = 0; kk < 6; kk++)
            bfrag[q][kk] = *(const bf16x8*)&wt[(size_t)n * KP + kk * 32 + sub * 8];
    }
    float bias[4];
#pragma unroll
    for (int q = 0; q < 4; q++) bias[q] = bcat[wave * 64 + q * 16 + li];
    __syncthreads();

    for (int mt = 0; mt < 4; mt++) {
        bf16x8 afrag[6];
#pragma unroll
        for (int kk = 0; kk < 6; kk++)
            afrag[kk] = *(const bf16x8*)&xs[(mt * 16 + li) * XS_STRIDE + kk * 32 + sub * 8];
#pragma unroll
        for (int q = 0; q < 4; q++) {
            f32x4 a = {0.f, 0.f, 0.f, 0.f};
#pragma unroll
            for (int kk = 0; kk < 6; kk++)
                a = __builtin_amdgcn_mfma_f32_16x16x32_bf16(afrag[kk], bfrag[q][kk], a, 0, 0, 0);
            int n = wave * 64 + q * 16 + li;
            __hip_bfloat16* dst = (n < HID) ? xlb : xrb;
            int nc = n & (HID - 1);
#pragma unroll
            for (int r = 0; r < 4; r++) {
                int row = node0 + mt * 16 + sub * 4 + r;
                dst[(size_t)row * HID + nc] = __float2bfloat16(a[r] + bias[q]);
            }
        }
    }
}

// ================= fused layer-1 attention =================
__global__ void __launch_bounds__(256) k_gat1(const int* __restrict__ rowptr,
                                              const int* __restrict__ csr,
                                              const __hip_bfloat16* __restrict__ xlb,
                                              const __hip_bfloat16* __restrict__ xrb,
                                              const float* __restrict__ att,
                                              const float* __restrict__ bias,
                                              float* __restrict__ h) {
    int wave = threadIdx.x >> 6, lane = threadIdx.x & 63;
    int d = blockIdx.x * 4 + wave;
    if (d >= N_NODES) return;
    int sub = lane >> 4, li = lane & 15;

    uint4 qr = ((const uint4*)(xrb + (size_t)d * HID))[li];
    float xrv[8]; unpack8(qr, xrv);
    float atv[8];
    {
        float4 t0 = ((const float4*)att)[li * 2];
        float4 t1 = ((const float4*)att)[li * 2 + 1];
        atv[0] = t0.x; atv[1] = t0.y; atv[2] = t0.z; atv[3] = t0.w;
        atv[4] = t1.x; atv[5] = t1.y; atv[6] = t1.z; atv[7] = t1.w;
    }
    int beg = rowptr[d], end = rowptr[d + 1];
    int iters = (end - beg + 3) >> 2;
    float l = 0.f, o[8];
#pragma unroll
    for (int t = 0; t < 8; t++) o[t] = 0.f;

    int j = beg + sub;
    bool valid = j < end;
    int s = valid ? csr[j] : 0;
    uint4 q = *(const uint4*)(xlb + (size_t)s * HID + li * 8);

    for (int it = 0; it < iters; it++) {
        float c[8]; unpack8(q, c);
        bool v = valid;
        j += 4;
        valid = j < end;
        int sn = valid ? csr[j] : 0;
        q = *(const uint4*)(xlb + (size_t)sn * HID + li * 8);

        float p = 0.f;
#pragma unroll
        for (int t = 0; t < 8; t++) p = fmaf(atv[t], lrelu(c[t] + xrv[t]), p);
        p += __shfl_xor(p, 1);
        p += __shfl_xor(p, 2);
        p += __shfl_xor(p, 4);
        p += __shfl_xor(p, 8);
        float a = v ? __expf(p) : 0.f;
        l += a;
#pragma unroll
        for (int t = 0; t < 8; t++) o[t] = fmaf(a, c[t], o[t]);
    }
    l += __shfl_xor(l, 16);
    l += __shfl_xor(l, 32);
#pragma unroll
    for (int t = 0; t < 8; t++) {
        o[t] += __shfl_xor(o[t], 16);
        o[t] += __shfl_xor(o[t], 32);
    }
    if (sub == 0) {
        float inv = 1.f / l;
        float4 bv0 = ((const float4*)bias)[li * 2];
        float4 bv1 = ((const float4*)bias)[li * 2 + 1];
        float4 r0, r1;
        r0.x = fmaf(o[0], inv, bv0.x); r0.y = fmaf(o[1], inv, bv0.y);
        r0.z = fmaf(o[2], inv, bv0.z); r0.w = fmaf(o[3], inv, bv0.w);
        r1.x = fmaf(o[4], inv, bv1.x); r1.y = fmaf(o[5], inv, bv1.y);
        r1.z = fmaf(o[6], inv, bv1.z); r1.w = fmaf(o[7], inv, bv1.w);
        r0.x = fmaxf(r0.x, 0.f); r0.y = fmaxf(r0.y, 0.f);
        r0.z = fmaxf(r0.z, 0.f); r0.w = fmaxf(r0.w, 0.f);
        r1.x = fmaxf(r1.x, 0.f); r1.y = fmaxf(r1.y, 0.f);
        r1.z = fmaxf(r1.z, 0.f); r1.w = fmaxf(r1.w, 0.f);
        float4* hp = (float4*)(h + (size_t)d * HID + li * 8);
        hp[0] = r0;
        hp[1] = r1;
    }
}

// ================= layer-2 GEMMs: wave per node, shuffle K-reduce ============
__global__ void __launch_bounds__(256) k_gemm2(const float* __restrict__ h,
                                               const float* __restrict__ wb,
                                               float* __restrict__ xl2, float* __restrict__ xr2) {
    const float* W2l = wb + WO_W2L;
    const float* b2l = wb + WO_B2L;
    const float* W2r = wb + WO_W2R;
    const float* b2r = wb + WO_B2R;
    int wave = threadIdx.x >> 6, lane = threadIdx.x & 63;
    int node = blockIdx.x * 4 + wave;
    if (node >= N_NODES) return;
    const float* hr = h + (size_t)node * HID;
    float h0 = hr[lane], h1 = hr[lane + 64];
    float al0 = h0 * W2l[lane * 2 + 0] + h1 * W2l[(lane + 64) * 2 + 0];
    float al1 = h0 * W2l[lane * 2 + 1] + h1 * W2l[(lane + 64) * 2 + 1];
    float ar0 = h0 * W2r[lane * 2 + 0] + h1 * W2r[(lane + 64) * 2 + 0];
    float ar1 = h0 * W2r[lane * 2 + 1] + h1 * W2r[(lane + 64) * 2 + 1];
#pragma unroll
    for (int off = 32; off > 0; off >>= 1) {
        al0 += __shfl_down(al0, off);
        al1 += __shfl_down(al1, off);
        ar0 += __shfl_down(ar0, off);
        ar1 += __shfl_down(ar1, off);
    }
    if (lane == 0) {
        xl2[node * 2 + 0] = al0 + b2l[0];
        xl2[node * 2 + 1] = al1 + b2l[1];
        xr2[node * 2 + 0] = ar0 + b2r[0];
        xr2[node * 2 + 1] = ar1 + b2r[1];
    }
}

// ================= fused layer-2 attention: thread per dst node ==============
__global__ void __launch_bounds__(256) k_gat2(const int* __restrict__ rowptr,
                                              const int* __restrict__ csr,
                                              const float* __restrict__ xl2,
                                              const float* __restrict__ xr2,
                                              const float* __restrict__ wb,
                                              const unsigned* __restrict__ flag,
                                              void* __restrict__ dout) {
    int d = blockIdx.x * 256 + threadIdx.x;
    if (d >= N_NODES) return;
    float xr0 = xr2[d * 2 + 0], xr1 = xr2[d * 2 + 1];
    float at0 = wb[WO_ATT2], at1 = wb[WO_ATT2 + 1];
    int beg = rowptr[d], end = rowptr[d + 1];
    float l = 0.f, o0 = 0.f, o1 = 0.f;
    for (int j = beg; j < end; j++) {
        int s = csr[j];
        float b0 = xl2[s * 2 + 0], b1 = xl2[s * 2 + 1];
        float p = at0 * lrelu(b0 + xr0) + at1 * lrelu(b1 + xr1);
        float a = __expf(p);
        l += a;
        o0 = fmaf(a, b0, o0);
        o1 = fmaf(a, b1, o1);
    }
    float inv = 1.f / l;
    float v0 = fmaf(o0, inv, wb[WO_BIAS2 + 0]);
    float v1 = fmaf(o1, inv, wb[WO_BIAS2 + 1]);
    if (*flag) {
        ((__hip_bfloat16*)dout)[d * 2 + 0] = __float2bfloat16(v0);
        ((__hip_bfloat16*)dout)[d * 2 + 1] = __float2bfloat16(v1);
    } else {
        ((float*)dout)[d * 2 + 0] = v0;
        ((float*)dout)[d * 2 + 1] = v1;
    }
}

extern "C" void kernel_launch(void* const* d_in, const int* in_sizes, int n_in,
                              void* d_out, int out_size, void* d_ws, size_t ws_size,
                              hipStream_t stream) {
    char* w = (char*)d_ws;
    unsigned* flag = (unsigned*)(w + (size_t)OFF_FLAG * 4);
    float* wb = (float*)(w + (size_t)OFF_W * 4);
    unsigned short* xb = (unsigned short*)(w + (size_t)OFF_XB * 4);
    unsigned short* wt = (unsigned short*)(w + (size_t)OFF_WT * 4);
    float* bcat = (float*)(w + (size_t)OFF_BCAT * 4);
    __hip_bfloat16* xlb = (__hip_bfloat16*)(w + (size_t)OFF_XLB * 4);
    __hip_bfloat16* xrb = (__hip_bfloat16*)(w + (size_t)OFF_XRB * 4);
    float* h = (float*)(w + (size_t)OFF_H * 4);
    int* csr = (int*)(w + (size_t)OFF_CSR * 4);
    int* rowptr = (int*)(w + (size_t)OFF_ROWPTR * 4);
    int* cursor = (int*)(w + (size_t)OFF_CURSOR * 4);
    int* bsum = (int*)(w + (size_t)OFF_BSUM * 4);
    float* xl2 = (float*)(w + (size_t)OFF_XL2 * 4);
    float* xr2 = (float*)(w + (size_t)OFF_XR2 * 4);
    const int* esrc = (const int*)d_in[1];
    const int* edst = (const int*)d_in[2];

    k_detect<<<1, 256, 0, stream>>>((const unsigned short*)d_in[0], flag);
    k_cvt_w<<<(W_TOTAL + 255) / 256, 256, 0, stream>>>(flag,
        d_in[3], d_in[4], d_in[5], d_in[6], d_in[7], d_in[8],
        d_in[9], d_in[10], d_in[11], d_in[12], d_in[13], d_in[14], wb);
    k_cvt_x<<<(NPAD * KP + 255) / 256, 256, 0, stream>>>(d_in[0], flag, xb);
    k_cvt_wt<<<(256 * KP + 255) / 256, 256, 0, stream>>>(wb, wt, bcat);

    // ---- CSR build (shared by both layers) ----
    hipMemsetAsync(cursor, 0, (size_t)N_NODES * 4, stream);
    k_hist<<<(ETOT + 255) / 256, 256, 0, stream>>>(edst, cursor);
    k_scan1<<<NBLK, 256, 0, stream>>>(cursor, rowptr, bsum);
    k_scan2<<<1, 512, 0, stream>>>(bsum, rowptr);
    k_scan3<<<NBLK, 256, 0, stream>>>(rowptr, bsum, cursor);
    k_scatter<<<(ETOT + 255) / 256, 256, 0, stream>>>(esrc, edst, cursor, csr);

    // ---- layer 1 ----
    k_gemm1_mfma<<<NPAD / 64, 256, 0, stream>>>(xb, wt, bcat, xlb, xrb);
    k_gat1<<<(N_NODES + 3) / 4, 256, 0, stream>>>(rowptr, csr, xlb, xrb,
                                                  wb + WO_ATT1, wb + WO_BIAS1, h);

    // ---- layer 2 ----
    k_gemm2<<<(N_NODES + 3) / 4, 256, 0, stream>>>(h, wb, xl2, xr2);
    k_gat2<<<(N_NODES + 255) / 256, 256, 0, stream>>>(rowptr, csr, xl2, xr2,
                                                      wb, flag, d_out);
}

// Round 5
// 478.151 us; speedup vs baseline: 3.7311x; 1.0667x over previous
//
#include <hip/hip_runtime.h>
#include <hip/hip_bf16.h>

#define N_NODES 100000
#define NPAD 100032                         // 64-row-aligned node count
#define N_EDGES 1600000
#define ETOT (N_EDGES + N_NODES)
#define NFEAT 165
#define KP 192                              // K padded to 32-multiple
#define HID 128
#define NCLS 2
#define NEG 0.2f

// CSR radix-build parameters
#define NBUCK 391                           // ceil(N_NODES/256); bucket = dst >> 8
#define CHUNK 16384
#define NCHUNK 104                          // ceil(ETOT/CHUNK)

typedef short bf16x8 __attribute__((ext_vector_type(8)));
typedef float f32x4 __attribute__((ext_vector_type(4)));

// ---- workspace layout (units of 4 bytes) ----
#define OFF_FLAG 0
#define OFF_W 16
// weight sub-offsets (within wb = ws + OFF_W)
#define WO_W1L 0
#define WO_B1L 21120
#define WO_W1R 21248
#define WO_B1R 42368
#define WO_ATT1 42496
#define WO_BIAS1 42624
#define WO_W2L 42752
#define WO_B2L 43008
#define WO_W2R 43010
#define WO_B2R 43266
#define WO_ATT2 43268
#define WO_BIAS2 43270
#define W_TOTAL 43272

#define OFF_XB   43392                      // bf16 x padded [NPAD][192]
#define OFF_WT   (OFF_XB + NPAD * KP / 2)   // bf16 WT [256][192]
#define OFF_BCAT (OFF_WT + 256 * KP / 2)    // fp32 bias concat [256]
#define OFF_XLB  (OFF_BCAT + 256)           // bf16 xl rows [NPAD][128]
#define OFF_XRB  (OFF_XLB + NPAD * HID / 2) // bf16 xr rows
#define OFF_H    (OFF_XRB + NPAD * HID / 2) // fp32 h [N][128]; pairs alias (dead until gat1)
#define OFF_CSR  (OFF_H + N_NODES * HID)    // csr_src[ETOT]
#define OFF_ROWPTR (OFF_CSR + ETOT)         // rowptr[N_NODES+1]
#define OFF_S    (OFF_ROWPTR + N_NODES + 8) // block-histogram / scanned offsets [NBUCK*NCHUNK]
#define OFF_XL2  (OFF_S + NBUCK * NCHUNK + 8)
#define OFF_XR2  (OFF_XL2 + N_NODES * NCLS)

__device__ __forceinline__ float bload(const void* p, size_t i) {
    unsigned u = ((const unsigned short*)p)[i];
    return __uint_as_float(u << 16);
}

// lrelu(v) = 0.6v + 0.4|v|
__device__ __forceinline__ float lrelu(float v) {
    return fmaf(0.4f, fabsf(v), 0.6f * v);
}

__device__ __forceinline__ void unpack8(uint4 q, float* f) {
    f[0] = __uint_as_float(q.x << 16); f[1] = __uint_as_float(q.x & 0xffff0000u);
    f[2] = __uint_as_float(q.y << 16); f[3] = __uint_as_float(q.y & 0xffff0000u);
    f[4] = __uint_as_float(q.z << 16); f[5] = __uint_as_float(q.z & 0xffff0000u);
    f[6] = __uint_as_float(q.w << 16); f[7] = __uint_as_float(q.w & 0xffff0000u);
}

__device__ __forceinline__ unsigned short f2b(float f) {
    __hip_bfloat16 b = __float2bfloat16(f);
    return *(unsigned short*)&b;
}

// ---- dtype detection ----
__global__ void k_detect(const unsigned short* __restrict__ x16, unsigned* flag) {
    __shared__ int cnt;
    if (threadIdx.x == 0) cnt = 0;
    __syncthreads();
    int c = 0;
    for (int t = 0; t < 2; t++) {
        unsigned short h = x16[threadIdx.x * 2 + t];
        unsigned e = (h >> 7) & 0xFF;
        if ((h & 0x7FFF) == 0 || (e >= 100 && e <= 140)) c++;
    }
    atomicAdd(&cnt, c);
    __syncthreads();
    if (threadIdx.x == 0) *flag = (cnt >= 384) ? 1u : 0u;
}

// ---- convert all weight tensors to fp32 in workspace ----
__global__ void k_cvt_w(const unsigned* __restrict__ flag,
                        const void* s0, const void* s1, const void* s2, const void* s3,
                        const void* s4, const void* s5, const void* s6, const void* s7,
                        const void* s8, const void* s9, const void* s10, const void* s11,
                        float* __restrict__ dst) {
    int i = blockIdx.x * blockDim.x + threadIdx.x;
    if (i >= W_TOTAL) return;
    const void* src; int off;
    if      (i < WO_B1L)   { src = s0;  off = i; }
    else if (i < WO_W1R)   { src = s1;  off = i - WO_B1L; }
    else if (i < WO_B1R)   { src = s2;  off = i - WO_W1R; }
    else if (i < WO_ATT1)  { src = s3;  off = i - WO_B1R; }
    else if (i < WO_BIAS1) { src = s4;  off = i - WO_ATT1; }
    else if (i < WO_W2L)   { src = s5;  off = i - WO_BIAS1; }
    else if (i < WO_B2L)   { src = s6;  off = i - WO_W2L; }
    else if (i < WO_W2R)   { src = s7;  off = i - WO_B2L; }
    else if (i < WO_B2R)   { src = s8;  off = i - WO_W2R; }
    else if (i < WO_ATT2)  { src = s9;  off = i - WO_B2R; }
    else if (i < WO_BIAS2) { src = s10; off = i - WO_ATT2; }
    else                   { src = s11; off = i - WO_BIAS2; }
    dst[i] = (*flag) ? bload(src, off) : ((const float*)src)[off];
}

// ---- x -> bf16, K padded to 192, rows padded to NPAD ----
__global__ void k_cvt_x(const void* __restrict__ x, const unsigned* __restrict__ flag,
                        unsigned short* __restrict__ xb) {
    int i = blockIdx.x * 256 + threadIdx.x;
    if (i >= NPAD * KP) return;
    int row = i / KP, col = i - row * KP;
    unsigned short v = 0;
    if (row < N_NODES && col < NFEAT) {
        size_t g = (size_t)row * NFEAT + col;
        if (*flag) v = ((const unsigned short*)x)[g];
        else       v = f2b(((const float*)x)[g]);
    }
    xb[i] = v;
}

// ---- pack W1l|W1r transposed to bf16 WT[256][192] + bias concat ----
__global__ void k_cvt_wt(const float* __restrict__ wb, unsigned short* __restrict__ wt,
                         float* __restrict__ bcat) {
    int i = blockIdx.x * 256 + threadIdx.x;
    if (i >= 256 * KP) return;
    int n = i / KP, k = i - n * KP;
    float f = 0.f;
    if (k < NFEAT)
        f = (n < HID) ? wb[WO_W1L + k * HID + n] : wb[WO_W1R + k * HID + (n - HID)];
    wt[i] = f2b(f);
    if (k == 0) bcat[n] = (n < HID) ? wb[WO_B1L + n] : wb[WO_B1R + (n - HID)];
}

// ================= CSR build: two-level counting sort =================
// Pass A1: per-(bucket, block) histogram. bh layout is bucket-major so the
// scan order (bucket 0 blocks 0..103, bucket 1 ...) matches output order.
__global__ void __launch_bounds__(256) k_pa_hist(const int* __restrict__ edst,
                                                 int* __restrict__ bh) {
    __shared__ int hist[NBUCK];
    for (int i = threadIdx.x; i < NBUCK; i += 256) hist[i] = 0;
    __syncthreads();
    int base = blockIdx.x * CHUNK;
    for (int i = threadIdx.x; i < CHUNK; i += 256) {
        int e = base + i;
        if (e >= ETOT) break;
        int d = (e < N_EDGES) ? edst[e] : (e - N_EDGES);
        atomicAdd(&hist[d >> 8], 1);
    }
    __syncthreads();
    for (int b = threadIdx.x; b < NBUCK; b += 256)
        bh[b * NCHUNK + blockIdx.x] = hist[b];
}

// Pass A2: exclusive scan of the NBUCK*NCHUNK counts, in place.
__global__ void __launch_bounds__(512) k_pa_scan(int* __restrict__ S,
                                                 int* __restrict__ rowptr) {
    __shared__ int lds[512];
    const int TOT = NBUCK * NCHUNK;
    const int per = (TOT + 511) / 512;
    int t = threadIdx.x;
    int beg = t * per;
    int sum = 0;
    for (int k = 0; k < per; k++) {
        int i = beg + k;
        if (i < TOT) sum += S[i];
    }
    lds[t] = sum;
    __syncthreads();
    for (int off = 1; off < 512; off <<= 1) {
        int v = lds[t];
        if (t >= off) v += lds[t - off];
        __syncthreads();
        lds[t] = v;
        __syncthreads();
    }
    int carry = (t == 0) ? 0 : lds[t - 1];
    for (int k = 0; k < per; k++) {
        int i = beg + k;
        if (i < TOT) {
            int v = S[i];
            S[i] = carry;
            carry += v;
        }
    }
    if (t == 0) rowptr[N_NODES] = ETOT;
}

// Pass A3: scatter (src,dst) pairs into bucket-grouped runs. Each block owns a
// private contiguous run per bucket (no global atomics; dense writes).
__global__ void __launch_bounds__(256) k_pa_scatter(const int* __restrict__ esrc,
                                                    const int* __restrict__ edst,
                                                    const int* __restrict__ S,
                                                    int2* __restrict__ pairs) {
    __shared__ int cur[NBUCK];
    for (int i = threadIdx.x; i < NBUCK; i += 256)
        cur[i] = S[i * NCHUNK + blockIdx.x];
    __syncthreads();
    int base = blockIdx.x * CHUNK;
    for (int i = threadIdx.x; i < CHUNK; i += 256) {
        int e = base + i;
        if (e >= ETOT) break;
        int s = (e < N_EDGES) ? esrc[e] : (e - N_EDGES);
        int d = (e < N_EDGES) ? edst[e] : (e - N_EDGES);
        int p = atomicAdd(&cur[d >> 8], 1);
        pairs[p] = make_int2(s, d);
    }
}

// Pass B: one block per bucket. Local 256-node counting sort; emits rowptr for
// its nodes and the final csr (contiguous ~17 KB window, L2-hot).
__global__ void __launch_bounds__(256) k_bsort(const int* __restrict__ S,
                                               const int2* __restrict__ pairs,
                                               int* __restrict__ rowptr,
                                               int* __restrict__ csr) {
    __shared__ int hist[256];
    __shared__ int cur[256];
    int b = blockIdx.x, t = threadIdx.x;
    int beg = S[b * NCHUNK];
    int end = (b == NBUCK - 1) ? ETOT : S[(b + 1) * NCHUNK];
    hist[t] = 0;
    __syncthreads();
    for (int j = beg + t; j < end; j += 256)
        atomicAdd(&hist[pairs[j].y & 255], 1);
    __syncthreads();
    for (int off = 1; off < 256; off <<= 1) {   // inclusive scan
        int v = hist[t];
        if (t >= off) v += hist[t - off];
        __syncthreads();
        hist[t] = v;
        __syncthreads();
    }
    int excl = (t == 0) ? 0 : hist[t - 1];
    int node = b * 256 + t;
    if (node < N_NODES) rowptr[node] = beg + excl;
    cur[t] = beg + excl;
    __syncthreads();
    for (int j = beg + t; j < end; j += 256) {
        int2 pr = pairs[j];
        int p = atomicAdd(&cur[pr.y & 255], 1);
        csr[p] = pr.x;
    }
}

// ================= layer-1 GEMM via bf16 MFMA =================
#define XS_STRIDE 200
__global__ void __launch_bounds__(256) k_gemm1_mfma(
        const unsigned short* __restrict__ xb,
        const unsigned short* __restrict__ wt,
        const float* __restrict__ bcat,
        __hip_bfloat16* __restrict__ xlb,
        __hip_bfloat16* __restrict__ xrb) {
    __shared__ unsigned short xs[64 * XS_STRIDE];
    int tid = threadIdx.x;
    int wave = tid >> 6, lane = tid & 63;
    int sub = lane >> 4, li = lane & 15;
    int node0 = blockIdx.x * 64;

    for (int c = tid; c < 64 * 24; c += 256) {
        int r = c / 24, off = (c - r * 24) * 8;
        *(uint4*)&xs[r * XS_STRIDE + off] =
            *(const uint4*)&xb[(size_t)(node0 + r) * KP + off];
    }

    bf16x8 bfrag[4][6];
#pragma unroll
    for (int q = 0; q < 4; q++) {
        int n = wave * 64 + q * 16 + li;
#pragma unroll
        for (int kk = 0; kk < 6; kk++)
            bfrag[q][kk] = *(const bf16x8*)&wt[(size_t)n * KP + kk * 32 + sub * 8];
    }
    float bias[4];
#pragma unroll
    for (int q = 0; q < 4; q++) bias[q] = bcat[wave * 64 + q * 16 + li];
    __syncthreads();

    for (int mt = 0; mt < 4; mt++) {
        bf16x8 afrag[6];
#pragma unroll
        for (int kk = 0; kk < 6; kk++)
            afrag[kk] = *(const bf16x8*)&xs[(mt * 16 + li) * XS_STRIDE + kk * 32 + sub * 8];
#pragma unroll
        for (int q = 0; q < 4; q++) {
            f32x4 a = {0.f, 0.f, 0.f, 0.f};
#pragma unroll
            for (int kk = 0; kk < 6; kk++)
                a = __builtin_amdgcn_mfma_f32_16x16x32_bf16(afrag[kk], bfrag[q][kk], a, 0, 0, 0);
            int n = wave * 64 + q * 16 + li;
            __hip_bfloat16* dst = (n < HID) ? xlb : xrb;
            int nc = n & (HID - 1);
#pragma unroll
            for (int r = 0; r < 4; r++) {
                int row = node0 + mt * 16 + sub * 4 + r;
                dst[(size_t)row * HID + nc] = __float2bfloat16(a[r] + bias[q]);
            }
        }
    }
}

// ================= fused layer-1 attention =================
__global__ void __launch_bounds__(256) k_gat1(const int* __restrict__ rowptr,
                                              const int* __restrict__ csr,
                                              const __hip_bfloat16* __restrict__ xlb,
                                              const __hip_bfloat16* __restrict__ xrb,
                                              const float* __restrict__ att,
                                              const float* __restrict__ bias,
                                              float* __restrict__ h) {
    int wave = threadIdx.x >> 6, lane = threadIdx.x & 63;
    int d = blockIdx.x * 4 + wave;
    if (d >= N_NODES) return;
    int sub = lane >> 4, li = lane & 15;

    uint4 qr = ((const uint4*)(xrb + (size_t)d * HID))[li];
    float xrv[8]; unpack8(qr, xrv);
    float atv[8];
    {
        float4 t0 = ((const float4*)att)[li * 2];
        float4 t1 = ((const float4*)att)[li * 2 + 1];
        atv[0] = t0.x; atv[1] = t0.y; atv[2] = t0.z; atv[3] = t0.w;
        atv[4] = t1.x; atv[5] = t1.y; atv[6] = t1.z; atv[7] = t1.w;
    }
    int beg = rowptr[d], end = rowptr[d + 1];
    int iters = (end - beg + 3) >> 2;
    float l = 0.f, o[8];
#pragma unroll
    for (int t = 0; t < 8; t++) o[t] = 0.f;

    int j = beg + sub;
    bool valid = j < end;
    int s = valid ? csr[j] : 0;
    uint4 q = *(const uint4*)(xlb + (size_t)s * HID + li * 8);

    for (int it = 0; it < iters; it++) {
        float c[8]; unpack8(q, c);
        bool v = valid;
        j += 4;
        valid = j < end;
        int sn = valid ? csr[j] : 0;
        q = *(const uint4*)(xlb + (size_t)sn * HID + li * 8);

        float p = 0.f;
#pragma unroll
        for (int t = 0; t < 8; t++) p = fmaf(atv[t], lrelu(c[t] + xrv[t]), p);
        p += __shfl_xor(p, 1);
        p += __shfl_xor(p, 2);
        p += __shfl_xor(p, 4);
        p += __shfl_xor(p, 8);
        float a = v ? __expf(p) : 0.f;
        l += a;
#pragma unroll
        for (int t = 0; t < 8; t++) o[t] = fmaf(a, c[t], o[t]);
    }
    l += __shfl_xor(l, 16);
    l += __shfl_xor(l, 32);
#pragma unroll
    for (int t = 0; t < 8; t++) {
        o[t] += __shfl_xor(o[t], 16);
        o[t] += __shfl_xor(o[t], 32);
    }
    if (sub == 0) {
        float inv = 1.f / l;
        float4 bv0 = ((const float4*)bias)[li * 2];
        float4 bv1 = ((const float4*)bias)[li * 2 + 1];
        float4 r0, r1;
        r0.x = fmaf(o[0], inv, bv0.x); r0.y = fmaf(o[1], inv, bv0.y);
        r0.z = fmaf(o[2], inv, bv0.z); r0.w = fmaf(o[3], inv, bv0.w);
        r1.x = fmaf(o[4], inv, bv1.x); r1.y = fmaf(o[5], inv, bv1.y);
        r1.z = fmaf(o[6], inv, bv1.z); r1.w = fmaf(o[7], inv, bv1.w);
        r0.x = fmaxf(r0.x, 0.f); r0.y = fmaxf(r0.y, 0.f);
        r0.z = fmaxf(r0.z, 0.f); r0.w = fmaxf(r0.w, 0.f);
        r1.x = fmaxf(r1.x, 0.f); r1.y = fmaxf(r1.y, 0.f);
        r1.z = fmaxf(r1.z, 0.f); r1.w = fmaxf(r1.w, 0.f);
        float4* hp = (float4*)(h + (size_t)d * HID + li * 8);
        hp[0] = r0;
        hp[1] = r1;
    }
}

// ================= layer-2 GEMMs: wave per node, shuffle K-reduce ============
__global__ void __launch_bounds__(256) k_gemm2(const float* __restrict__ h,
                                               const float* __restrict__ wb,
                                               float* __restrict__ xl2, float* __restrict__ xr2) {
    const float* W2l = wb + WO_W2L;
    const float* b2l = wb + WO_B2L;
    const float* W2r = wb + WO_W2R;
    const float* b2r = wb + WO_B2R;
    int wave = threadIdx.x >> 6, lane = threadIdx.x & 63;
    int node = blockIdx.x * 4 + wave;
    if (node >= N_NODES) return;
    const float* hr = h + (size_t)node * HID;
    float h0 = hr[lane], h1 = hr[lane + 64];
    float al0 = h0 * W2l[lane * 2 + 0] + h1 * W2l[(lane + 64) * 2 + 0];
    float al1 = h0 * W2l[lane * 2 + 1] + h1 * W2l[(lane + 64) * 2 + 1];
    float ar0 = h0 * W2r[lane * 2 + 0] + h1 * W2r[(lane + 64) * 2 + 0];
    float ar1 = h0 * W2r[lane * 2 + 1] + h1 * W2r[(lane + 64) * 2 + 1];
#pragma unroll
    for (int off = 32; off > 0; off >>= 1) {
        al0 += __shfl_down(al0, off);
        al1 += __shfl_down(al1, off);
        ar0 += __shfl_down(ar0, off);
        ar1 += __shfl_down(ar1, off);
    }
    if (lane == 0) {
        xl2[node * 2 + 0] = al0 + b2l[0];
        xl2[node * 2 + 1] = al1 + b2l[1];
        xr2[node * 2 + 0] = ar0 + b2r[0];
        xr2[node * 2 + 1] = ar1 + b2r[1];
    }
}

// ================= fused layer-2 attention: thread per dst node ==============
__global__ void __launch_bounds__(256) k_gat2(const int* __restrict__ rowptr,
                                              const int* __restrict__ csr,
                                              const float* __restrict__ xl2,
                                              const float* __restrict__ xr2,
                                              const float* __restrict__ wb,
                                              const unsigned* __restrict__ flag,
                                              void* __restrict__ dout) {
    int d = blockIdx.x * 256 + threadIdx.x;
    if (d >= N_NODES) return;
    float xr0 = xr2[d * 2 + 0], xr1 = xr2[d * 2 + 1];
    float at0 = wb[WO_ATT2], at1 = wb[WO_ATT2 + 1];
    int beg = rowptr[d], end = rowptr[d + 1];
    float l = 0.f, o0 = 0.f, o1 = 0.f;
    for (int j = beg; j < end; j++) {
        int s = csr[j];
        float b0 = xl2[s * 2 + 0], b1 = xl2[s * 2 + 1];
        float p = at0 * lrelu(b0 + xr0) + at1 * lrelu(b1 + xr1);
        float a = __expf(p);
        l += a;
        o0 = fmaf(a, b0, o0);
        o1 = fmaf(a, b1, o1);
    }
    float inv = 1.f / l;
    float v0 = fmaf(o0, inv, wb[WO_BIAS2 + 0]);
    float v1 = fmaf(o1, inv, wb[WO_BIAS2 + 1]);
    if (*flag) {
        ((__hip_bfloat16*)dout)[d * 2 + 0] = __float2bfloat16(v0);
        ((__hip_bfloat16*)dout)[d * 2 + 1] = __float2bfloat16(v1);
    } else {
        ((float*)dout)[d * 2 + 0] = v0;
        ((float*)dout)[d * 2 + 1] = v1;
    }
}

extern "C" void kernel_launch(void* const* d_in, const int* in_sizes, int n_in,
                              void* d_out, int out_size, void* d_ws, size_t ws_size,
                              hipStream_t stream) {
    char* w = (char*)d_ws;
    unsigned* flag = (unsigned*)(w + (size_t)OFF_FLAG * 4);
    float* wb = (float*)(w + (size_t)OFF_W * 4);
    unsigned short* xb = (unsigned short*)(w + (size_t)OFF_XB * 4);
    unsigned short* wt = (unsigned short*)(w + (size_t)OFF_WT * 4);
    float* bcat = (float*)(w + (size_t)OFF_BCAT * 4);
    __hip_bfloat16* xlb = (__hip_bfloat16*)(w + (size_t)OFF_XLB * 4);
    __hip_bfloat16* xrb = (__hip_bfloat16*)(w + (size_t)OFF_XRB * 4);
    float* h = (float*)(w + (size_t)OFF_H * 4);
    int2* pairs = (int2*)(w + (size_t)OFF_H * 4);   // alias: dead before k_gat1
    int* csr = (int*)(w + (size_t)OFF_CSR * 4);
    int* rowptr = (int*)(w + (size_t)OFF_ROWPTR * 4);
    int* S = (int*)(w + (size_t)OFF_S * 4);
    float* xl2 = (float*)(w + (size_t)OFF_XL2 * 4);
    float* xr2 = (float*)(w + (size_t)OFF_XR2 * 4);
    const int* esrc = (const int*)d_in[1];
    const int* edst = (const int*)d_in[2];

    k_detect<<<1, 256, 0, stream>>>((const unsigned short*)d_in[0], flag);
    k_cvt_w<<<(W_TOTAL + 255) / 256, 256, 0, stream>>>(flag,
        d_in[3], d_in[4], d_in[5], d_in[6], d_in[7], d_in[8],
        d_in[9], d_in[10], d_in[11], d_in[12], d_in[13], d_in[14], wb);
    k_cvt_x<<<(NPAD * KP + 255) / 256, 256, 0, stream>>>(d_in[0], flag, xb);
    k_cvt_wt<<<(256 * KP + 255) / 256, 256, 0, stream>>>(wb, wt, bcat);

    // ---- CSR build: two-level counting sort (shared by both layers) ----
    k_pa_hist<<<NCHUNK, 256, 0, stream>>>(edst, S);
    k_pa_scan<<<1, 512, 0, stream>>>(S, rowptr);
    k_pa_scatter<<<NCHUNK, 256, 0, stream>>>(esrc, edst, S, pairs);
    k_bsort<<<NBUCK, 256, 0, stream>>>(S, pairs, rowptr, csr);

    // ---- layer 1 ----
    k_gemm1_mfma<<<NPAD / 64, 256, 0, stream>>>(xb, wt, bcat, xlb, xrb);
    k_gat1<<<(N_NODES + 3) / 4, 256, 0, stream>>>(rowptr, csr, xlb, xrb,
                                                  wb + WO_ATT1, wb + WO_BIAS1, h);

    // ---- layer 2 ----
    k_gemm2<<<(N_NODES + 3) / 4, 256, 0, stream>>>(h, wb, xl2, xr2);
    k_gat2<<<(N_NODES + 255) / 256, 256, 0, stream>>>(rowptr, csr, xl2, xr2,
                                                      wb, flag, d_out);
}